// Round 1
// baseline (1881.246 us; speedup 1.0000x reference)
//
#include <hip/hip_runtime.h>

#define DIV_UP(a,b) (((a)+(b)-1)/(b))
#define SCAN_B 1024
#define ROW_GRID 2048

// ---------------- CSR build ----------------
__global__ void count_k(const int* __restrict__ tgt, int* __restrict__ cnt, int E){
  int i = blockIdx.x*blockDim.x + threadIdx.x;
  if (i < E) atomicAdd(&cnt[tgt[i]], 1);
}

__global__ void blockscan_k(const int* __restrict__ cnt, int* __restrict__ off,
                            int* __restrict__ bsum, int N){
  __shared__ int sd[SCAN_B];
  int t = threadIdx.x; int g = blockIdx.x*SCAN_B + t;
  int v = (g < N) ? cnt[g] : 0;
  sd[t] = v; __syncthreads();
  for (int o = 1; o < SCAN_B; o <<= 1){
    int add = (t >= o) ? sd[t-o] : 0;
    __syncthreads();
    sd[t] += add;
    __syncthreads();
  }
  if (g < N) off[g] = sd[t] - v;               // exclusive within block
  if (t == SCAN_B-1) bsum[blockIdx.x] = sd[t]; // block total
}

__global__ void scan2_k(int* __restrict__ bsum, int nb){
  __shared__ int sd[SCAN_B];
  int t = threadIdx.x;
  int v = (t < nb) ? bsum[t] : 0;
  sd[t] = v; __syncthreads();
  for (int o = 1; o < SCAN_B; o <<= 1){
    int add = (t >= o) ? sd[t-o] : 0;
    __syncthreads();
    sd[t] += add;
    __syncthreads();
  }
  if (t < nb) bsum[t] = sd[t] - v;             // exclusive block bases
}

__global__ void addback_k(int* __restrict__ off, const int* __restrict__ bsum,
                          int* __restrict__ cur, int N){
  int g = blockIdx.x*blockDim.x + threadIdx.x;
  if (g < N){ int o = off[g] + bsum[g >> 10]; off[g] = o; cur[g] = o; }
}

__global__ void scatter_perm_k(const int* __restrict__ src, const int* __restrict__ tgt,
                               int* __restrict__ cur, int* __restrict__ perm, int E){
  int e = blockIdx.x*blockDim.x + threadIdx.x;
  if (e < E){ int p = atomicAdd(&cur[tgt[e]], 1); perm[p] = src[e]; }
}

// ---------------- generic row matmul: O[r][c] = B[c] + sum_k X[r][k]*W[k][c] ----------------
template<int K>
__global__ __launch_bounds__(256) void mm_k(const float* __restrict__ X,
    const float* __restrict__ W, const float* __restrict__ B,
    float* __restrict__ O, int N){
  const int lane = threadIdx.x & 63, w = threadIdx.x >> 6;
  float Wreg[K];
#pragma unroll
  for (int k = 0; k < K; ++k) Wreg[k] = W[k*64 + lane];
  const float bv = B[lane];
  for (int r = blockIdx.x*4 + w; r < N; r += gridDim.x*4){
    const float4* xr = reinterpret_cast<const float4*>(X + (size_t)r*K);
    float a0 = 0.f, a1 = 0.f, a2 = 0.f, a3 = 0.f;
#pragma unroll
    for (int kk = 0; kk < K/4; ++kk){
      float4 q = xr[kk];
      a0 += q.x*Wreg[kk*4+0]; a1 += q.y*Wreg[kk*4+1];
      a2 += q.z*Wreg[kk*4+2]; a3 += q.w*Wreg[kk*4+3];
    }
    O[(size_t)r*64 + lane] = bv + ((a0+a1)+(a2+a3));
  }
}

// ---------------- neighbor aggregate (sum/mean/max mixture) ----------------
__global__ __launch_bounds__(256) void gather_k(
    const float* __restrict__ xnl, const int* __restrict__ off,
    const int* __restrict__ cnt, const int* __restrict__ perm,
    const float* __restrict__ Z_agg, int layer, float* __restrict__ xn, int N){
  const int lane = threadIdx.x & 63, w = threadIdx.x >> 6;
  const float za0 = Z_agg[layer*3+0], za1 = Z_agg[layer*3+1], za2 = Z_agg[layer*3+2];
  for (int r = blockIdx.x*4 + w; r < N; r += gridDim.x*4){
    const int e0 = off[r], deg = cnt[r];
    float ssum = 0.f, smax = -3.402823466e38f;
    for (int base = 0; base < deg; base += 64){
      int nrem = deg - base; if (nrem > 64) nrem = 64;
      int pe = (lane < nrem) ? perm[e0 + base + lane] : 0;
      int j = 0;
      for (; j + 4 <= nrem; j += 4){
        int s0 = __shfl(pe, j, 64),   s1 = __shfl(pe, j+1, 64);
        int s2 = __shfl(pe, j+2, 64), s3 = __shfl(pe, j+3, 64);
        float v0 = xnl[(size_t)s0*64 + lane];
        float v1 = xnl[(size_t)s1*64 + lane];
        float v2 = xnl[(size_t)s2*64 + lane];
        float v3 = xnl[(size_t)s3*64 + lane];
        ssum += v0; ssum += v1; ssum += v2; ssum += v3;
        smax = fmaxf(smax, fmaxf(fmaxf(v0, v1), fmaxf(v2, v3)));
      }
      for (; j < nrem; ++j){
        int si = __shfl(pe, j, 64);
        float v = xnl[(size_t)si*64 + lane];
        ssum += v; smax = fmaxf(smax, v);
      }
    }
    float mean = ssum / fmaxf((float)deg, 1.f);
    float mxv  = (deg > 0) ? smax : 0.f;
    xn[(size_t)r*64 + lane] = za0*ssum + za1*mean + za2*mxv;
  }
}

// ---------------- fused: x_self, combine mixture, act mixture, layernorm ----------------
__global__ __launch_bounds__(256) void combine_k(
    const float* __restrict__ x_in, const float* __restrict__ xn_buf,
    const float* __restrict__ W_self, const float* __restrict__ b_self,
    const float* __restrict__ W_comb, const float* __restrict__ b_comb,
    const float* __restrict__ ln_g, const float* __restrict__ ln_b,
    const float* __restrict__ Z_comb, const float* __restrict__ Z_act,
    const float* __restrict__ prelu_w, int layer,
    float* __restrict__ emb_out, int N){
  __shared__ __align__(16) float sA[4][64];
  __shared__ __align__(16) float sB[4][64];
  const int lane = threadIdx.x & 63, w = threadIdx.x >> 6;
  float Ws[64];
#pragma unroll
  for (int k = 0; k < 64; ++k) Ws[k] = W_self[layer*4096 + k*64 + lane];
  float Wc[128];
#pragma unroll
  for (int k = 0; k < 128; ++k) Wc[k] = W_comb[layer*8192 + k*64 + lane];
  const float bs = b_self[layer*64 + lane], bc = b_comb[layer*64 + lane];
  const float lg = ln_g[layer*64 + lane],  lb = ln_b[layer*64 + lane];
  const float zc0 = Z_comb[layer*2+0], zc1 = Z_comb[layer*2+1];
  const float zt0 = Z_act[layer*2+0],  zt1 = Z_act[layer*2+1];
  const float pw = prelu_w[layer];
  for (int r = blockIdx.x*4 + w; r < N; r += gridDim.x*4){
    const float4* xr = reinterpret_cast<const float4*>(x_in + (size_t)r*64);
    float a0 = 0.f, a1 = 0.f, a2 = 0.f, a3 = 0.f;
#pragma unroll
    for (int kk = 0; kk < 16; ++kk){
      float4 q = xr[kk];
      a0 += q.x*Ws[kk*4+0]; a1 += q.y*Ws[kk*4+1];
      a2 += q.z*Ws[kk*4+2]; a3 += q.w*Ws[kk*4+3];
    }
    float xs = bs + ((a0+a1)+(a2+a3));
    float xn = xn_buf[(size_t)r*64 + lane];
    sA[w][lane] = xs; sB[w][lane] = xn;
    float c0 = 0.f, c1 = 0.f, c2 = 0.f, c3 = 0.f;
#pragma unroll
    for (int kk = 0; kk < 16; ++kk){
      float4 q = *reinterpret_cast<const float4*>(&sA[w][kk*4]);
      c0 += q.x*Wc[kk*4+0]; c1 += q.y*Wc[kk*4+1];
      c2 += q.z*Wc[kk*4+2]; c3 += q.w*Wc[kk*4+3];
    }
#pragma unroll
    for (int kk = 0; kk < 16; ++kk){
      float4 q = *reinterpret_cast<const float4*>(&sB[w][kk*4]);
      c0 += q.x*Wc[64+kk*4+0]; c1 += q.y*Wc[64+kk*4+1];
      c2 += q.z*Wc[64+kk*4+2]; c3 += q.w*Wc[64+kk*4+3];
    }
    float cc = bc + ((c0+c1)+(c2+c3));
    float h = zc0*(xs + xn) + zc1*cc;
    h = zt0*fmaxf(h, 0.f) + zt1*((h > 0.f) ? h : pw*h);
    // layernorm over 64 lanes
    float t = h;
#pragma unroll
    for (int o = 32; o; o >>= 1) t += __shfl_xor(t, o, 64);
    float mu = t * (1.f/64.f);
    float d = h - mu;
    float t2 = d*d;
#pragma unroll
    for (int o = 32; o; o >>= 1) t2 += __shfl_xor(t2, o, 64);
    h = d * rsqrtf(t2*(1.f/64.f) + 1e-5f) * lg + lb;
    emb_out[(size_t)r*64 + lane] = h;
  }
}

// ---------------- layer-connect mixture ----------------
__global__ __launch_bounds__(256) void lc_k(
    const float* __restrict__ emb_prev, const float* __restrict__ emb_new,
    const float* __restrict__ W_lc, const float* __restrict__ b_lc,
    const float* __restrict__ Z_lc, int layer, float* __restrict__ x_out, int N){
  const int lane = threadIdx.x & 63, w = threadIdx.x >> 6;
  float Wl[128];
#pragma unroll
  for (int k = 0; k < 128; ++k) Wl[k] = W_lc[layer*8192 + k*64 + lane];
  const float bl = b_lc[layer*64 + lane];
  const float z0 = Z_lc[layer*3+0], z1 = Z_lc[layer*3+1], z2 = Z_lc[layer*3+2];
  for (int r = blockIdx.x*4 + w; r < N; r += gridDim.x*4){
    const float4* pr = reinterpret_cast<const float4*>(emb_prev + (size_t)r*64);
    const float4* hr = reinterpret_cast<const float4*>(emb_new  + (size_t)r*64);
    float c0 = 0.f, c1 = 0.f, c2 = 0.f, c3 = 0.f;
#pragma unroll
    for (int kk = 0; kk < 16; ++kk){
      float4 q = pr[kk];
      c0 += q.x*Wl[kk*4+0]; c1 += q.y*Wl[kk*4+1];
      c2 += q.z*Wl[kk*4+2]; c3 += q.w*Wl[kk*4+3];
    }
#pragma unroll
    for (int kk = 0; kk < 16; ++kk){
      float4 q = hr[kk];
      c0 += q.x*Wl[64+kk*4+0]; c1 += q.y*Wl[64+kk*4+1];
      c2 += q.z*Wl[64+kk*4+2]; c3 += q.w*Wl[64+kk*4+3];
    }
    float pv = emb_prev[(size_t)r*64 + lane];
    float hv = emb_new[(size_t)r*64 + lane];
    float cc = bl + ((c0+c1)+(c2+c3));
    x_out[(size_t)r*64 + lane] = z0*hv + z1*(hv + pv) + z2*cc;
  }
}

// ---------------- layer-agg part 1: b_lagg + emb0@Wg[0:64] + emb1@Wg[64:128] ----------------
__global__ __launch_bounds__(256) void lagg1_k(
    const float* __restrict__ e0p, const float* __restrict__ e1p,
    const float* __restrict__ W_lagg, const float* __restrict__ b_lagg,
    float* __restrict__ mixp, int N){
  const int lane = threadIdx.x & 63, w = threadIdx.x >> 6;
  float Wg[128];
#pragma unroll
  for (int k = 0; k < 128; ++k) Wg[k] = W_lagg[k*64 + lane];
  const float bv = b_lagg[lane];
  for (int r = blockIdx.x*4 + w; r < N; r += gridDim.x*4){
    const float4* r0 = reinterpret_cast<const float4*>(e0p + (size_t)r*64);
    const float4* r1 = reinterpret_cast<const float4*>(e1p + (size_t)r*64);
    float c0 = 0.f, c1 = 0.f, c2 = 0.f, c3 = 0.f;
#pragma unroll
    for (int kk = 0; kk < 16; ++kk){
      float4 q = r0[kk];
      c0 += q.x*Wg[kk*4+0]; c1 += q.y*Wg[kk*4+1];
      c2 += q.z*Wg[kk*4+2]; c3 += q.w*Wg[kk*4+3];
    }
#pragma unroll
    for (int kk = 0; kk < 16; ++kk){
      float4 q = r1[kk];
      c0 += q.x*Wg[64+kk*4+0]; c1 += q.y*Wg[64+kk*4+1];
      c2 += q.z*Wg[64+kk*4+2]; c3 += q.w*Wg[64+kk*4+3];
    }
    mixp[(size_t)r*64 + lane] = bv + ((c0+c1)+(c2+c3));
  }
}

// ---------------- layer-agg part 2 + mixture ----------------
__global__ __launch_bounds__(256) void lagg2_k(
    const float* __restrict__ e0p, const float* __restrict__ e1p,
    const float* __restrict__ e2p, const float* __restrict__ e3p,
    const float* __restrict__ mixp, const float* __restrict__ W_lagg,
    const float* __restrict__ Z_lagg, float* __restrict__ mix_out, int N){
  const int lane = threadIdx.x & 63, w = threadIdx.x >> 6;
  float Wg[128];
#pragma unroll
  for (int k = 0; k < 128; ++k) Wg[k] = W_lagg[(128 + k)*64 + lane];
  const float zg0 = Z_lagg[0], zg1 = Z_lagg[1], zg2 = Z_lagg[2];
  for (int r = blockIdx.x*4 + w; r < N; r += gridDim.x*4){
    const float4* r2 = reinterpret_cast<const float4*>(e2p + (size_t)r*64);
    const float4* r3 = reinterpret_cast<const float4*>(e3p + (size_t)r*64);
    float c0 = 0.f, c1 = 0.f, c2 = 0.f, c3 = 0.f;
#pragma unroll
    for (int kk = 0; kk < 16; ++kk){
      float4 q = r2[kk];
      c0 += q.x*Wg[kk*4+0]; c1 += q.y*Wg[kk*4+1];
      c2 += q.z*Wg[kk*4+2]; c3 += q.w*Wg[kk*4+3];
    }
#pragma unroll
    for (int kk = 0; kk < 16; ++kk){
      float4 q = r3[kk];
      c0 += q.x*Wg[64+kk*4+0]; c1 += q.y*Wg[64+kk*4+1];
      c2 += q.z*Wg[64+kk*4+2]; c3 += q.w*Wg[64+kk*4+3];
    }
    float cat = mixp[(size_t)r*64 + lane] + ((c0+c1)+(c2+c3));
    float v0 = e0p[(size_t)r*64 + lane], v1 = e1p[(size_t)r*64 + lane];
    float v2 = e2p[(size_t)r*64 + lane], v3 = e3p[(size_t)r*64 + lane];
    float amax = fmaxf(fmaxf(v0, v1), fmaxf(v2, v3));
    mix_out[(size_t)r*64 + lane] = zg0*v3 + zg1*amax + zg2*cat;
  }
}

// ---------------- feed-forward head ----------------
__global__ __launch_bounds__(256) void ff_k(
    const float* __restrict__ mix, const float* __restrict__ W1g, const float* __restrict__ b1,
    const float* __restrict__ W2g, const float* __restrict__ b2,
    float* __restrict__ out, int N){
  __shared__ __align__(16) float sT[4][64];
  const int lane = threadIdx.x & 63, w = threadIdx.x >> 6;
  float W1[64], W2[64];
#pragma unroll
  for (int k = 0; k < 64; ++k) W1[k] = W1g[k*64 + lane];
#pragma unroll
  for (int k = 0; k < 64; ++k) W2[k] = W2g[k*64 + lane];
  const float bf1 = b1[lane], bf2 = b2[lane];
  for (int r = blockIdx.x*4 + w; r < N; r += gridDim.x*4){
    const float4* mr = reinterpret_cast<const float4*>(mix + (size_t)r*64);
    float a0 = 0.f, a1 = 0.f, a2 = 0.f, a3 = 0.f;
#pragma unroll
    for (int kk = 0; kk < 16; ++kk){
      float4 q = mr[kk];
      a0 += q.x*W1[kk*4+0]; a1 += q.y*W1[kk*4+1];
      a2 += q.z*W1[kk*4+2]; a3 += q.w*W1[kk*4+3];
    }
    float t = fmaxf(bf1 + ((a0+a1)+(a2+a3)), 0.f);
    sT[w][lane] = t;
    float c0 = 0.f, c1 = 0.f, c2 = 0.f, c3 = 0.f;
#pragma unroll
    for (int kk = 0; kk < 16; ++kk){
      float4 q = *reinterpret_cast<const float4*>(&sT[w][kk*4]);
      c0 += q.x*W2[kk*4+0]; c1 += q.y*W2[kk*4+1];
      c2 += q.z*W2[kk*4+2]; c3 += q.w*W2[kk*4+3];
    }
    out[(size_t)r*64 + lane] = bf2 + ((c0+c1)+(c2+c3));
  }
}

extern "C" void kernel_launch(void* const* d_in, const int* in_sizes, int n_in,
                              void* d_out, int out_size, void* d_ws, size_t ws_size,
                              hipStream_t stream){
  const float* x      = (const float*)d_in[0];
  const int*   ei     = (const int*)  d_in[1];
  const float* W_pre  = (const float*)d_in[2];
  const float* b_pre  = (const float*)d_in[3];
  const float* W_self = (const float*)d_in[4];
  const float* b_self = (const float*)d_in[5];
  const float* W_nbr  = (const float*)d_in[6];
  const float* b_nbr  = (const float*)d_in[7];
  const float* W_comb = (const float*)d_in[8];
  const float* b_comb = (const float*)d_in[9];
  const float* W_lc   = (const float*)d_in[10];
  const float* b_lc   = (const float*)d_in[11];
  const float* ln_g   = (const float*)d_in[12];
  const float* ln_b   = (const float*)d_in[13];
  const float* prelu  = (const float*)d_in[14];
  const float* W_lagg = (const float*)d_in[15];
  const float* b_lagg = (const float*)d_in[16];
  const float* W_ff1  = (const float*)d_in[17];
  const float* b_ff1  = (const float*)d_in[18];
  const float* W_ff2  = (const float*)d_in[19];
  const float* b_ff2  = (const float*)d_in[20];
  const float* Z_agg  = (const float*)d_in[21];
  const float* Z_comb = (const float*)d_in[22];
  const float* Z_act  = (const float*)d_in[23];
  const float* Z_lc   = (const float*)d_in[24];
  const float* Z_lagg = (const float*)d_in[25];

  const int N = in_sizes[0] / 128;
  const int E = in_sizes[1] / 2;
  const int* src = ei;
  const int* tgt = ei + E;

  // workspace carve (256B aligned slices)
  char* p = (char*)d_ws;
  auto carve = [&](size_t bytes)->void*{
    void* q = (void*)p;
    p += (bytes + 255) & ~(size_t)255;
    return q;
  };
  int*   cnt_i = (int*)carve((size_t)N * 4);
  int*   off   = (int*)carve((size_t)N * 4);
  int*   cur   = (int*)carve((size_t)N * 4);
  int*   bsum  = (int*)carve(4096 * 4);
  int*   perm  = (int*)carve((size_t)E * 4);
  float* emb0  = (float*)carve((size_t)N * 64 * 4);
  float* emb1  = (float*)carve((size_t)N * 64 * 4);
  float* emb2  = (float*)carve((size_t)N * 64 * 4);
  float* xbuf  = (float*)carve((size_t)N * 64 * 4);
  float* xnl   = (float*)carve((size_t)N * 64 * 4);
  float* xn    = (float*)carve((size_t)N * 64 * 4);
  float* emb3  = (float*)d_out;     // emb3 lives in d_out until the head runs

  // ---- CSR build (once per launch; no big atomic scatter) ----
  hipMemsetAsync(cnt_i, 0, (size_t)N * 4, stream);
  count_k<<<DIV_UP(E,256),256,0,stream>>>(tgt, cnt_i, E);
  const int nb = DIV_UP(N, SCAN_B);
  blockscan_k<<<nb,SCAN_B,0,stream>>>(cnt_i, off, bsum, N);
  scan2_k<<<1,SCAN_B,0,stream>>>(bsum, nb);
  addback_k<<<DIV_UP(N,256),256,0,stream>>>(off, bsum, cur, N);
  scatter_perm_k<<<DIV_UP(E,256),256,0,stream>>>(src, tgt, cur, perm, E);

  // ---- preprocess ----
  mm_k<128><<<ROW_GRID,256,0,stream>>>(x, W_pre, b_pre, emb0, N);

  // ---- layers ----
  float* embs[4] = {emb0, emb1, emb2, emb3};
  const float* xin = emb0;
  for (int i = 0; i < 3; ++i){
    mm_k<64><<<ROW_GRID,256,0,stream>>>(xin, W_nbr + i*4096, b_nbr + i*64, xnl, N);
    gather_k<<<4096,256,0,stream>>>(xnl, off, cnt_i, perm, Z_agg, i, xn, N);
    combine_k<<<ROW_GRID,256,0,stream>>>(xin, xn, W_self, b_self, W_comb, b_comb,
                                         ln_g, ln_b, Z_comb, Z_act, prelu, i,
                                         embs[i+1], N);
    if (i < 2){
      lc_k<<<ROW_GRID,256,0,stream>>>(embs[i], embs[i+1], W_lc, b_lc, Z_lc, i, xbuf, N);
      xin = xbuf;
    }
  }

  // ---- layer agg + head ----
  lagg1_k<<<ROW_GRID,256,0,stream>>>(emb0, emb1, W_lagg, b_lagg, xbuf, N);
  lagg2_k<<<ROW_GRID,256,0,stream>>>(emb0, emb1, emb2, emb3, xbuf, W_lagg, Z_lagg, xnl, N);
  ff_k<<<ROW_GRID,256,0,stream>>>(xnl, W_ff1, b_ff1, W_ff2, b_ff2, (float*)d_out, N);
}

// Round 2
// 606.972 us; speedup vs baseline: 3.0994x; 3.0994x over previous
//
#include <hip/hip_runtime.h>

typedef unsigned short u16;
typedef unsigned int u32;
using bfrag = __attribute__((ext_vector_type(8))) short;
using f4v   = __attribute__((ext_vector_type(4))) float;

#define DIV_UP(a,b) (((a)+(b)-1)/(b))
#define SCAN_B 1024
#define MFMA(a,b,c) __builtin_amdgcn_mfma_f32_16x16x32_bf16(a,b,c,0,0,0)

__device__ inline u16 f2bf(float f){
  union { float f; u32 u; } v; v.f = f;
  u32 u = v.u;
  return (u16)((u + 0x7fffu + ((u >> 16) & 1u)) >> 16);
}
__device__ inline float bf2f(u16 h){
  union { u32 u; float f; } v; v.u = ((u32)h) << 16;
  return v.f;
}
__device__ inline bfrag ldA(const u16* A, long r, int koff, int lane){
  return *reinterpret_cast<const bfrag*>(A + r*64 + koff + ((lane>>4)<<3));
}
__device__ inline bfrag ldW(const u16* Wf, int kb, int cb, int lane){
  return *reinterpret_cast<const bfrag*>(Wf + (((kb*4+cb)*64 + lane)<<3));
}

// ---------------- CSR build ----------------
__global__ void count_k(const int* __restrict__ tgt, int* __restrict__ cnt, int E){
  int i = blockIdx.x*blockDim.x + threadIdx.x;
  if (i < E) atomicAdd(&cnt[tgt[i]], 1);
}
__global__ void blockscan_k(const int* __restrict__ cnt, int* __restrict__ off,
                            int* __restrict__ bsum, int N){
  __shared__ int sd[SCAN_B];
  int t = threadIdx.x; int g = blockIdx.x*SCAN_B + t;
  int v = (g < N) ? cnt[g] : 0;
  sd[t] = v; __syncthreads();
  for (int o = 1; o < SCAN_B; o <<= 1){
    int add = (t >= o) ? sd[t-o] : 0;
    __syncthreads(); sd[t] += add; __syncthreads();
  }
  if (g < N) off[g] = sd[t] - v;
  if (t == SCAN_B-1) bsum[blockIdx.x] = sd[t];
}
__global__ void scan2_k(int* __restrict__ bsum, int nb){
  __shared__ int sd[SCAN_B];
  int t = threadIdx.x;
  int v = (t < nb) ? bsum[t] : 0;
  sd[t] = v; __syncthreads();
  for (int o = 1; o < SCAN_B; o <<= 1){
    int add = (t >= o) ? sd[t-o] : 0;
    __syncthreads(); sd[t] += add; __syncthreads();
  }
  if (t < nb) bsum[t] = sd[t] - v;
}
__global__ void addback_k(int* __restrict__ off, const int* __restrict__ bsum,
                          int* __restrict__ cur, int N){
  int g = blockIdx.x*blockDim.x + threadIdx.x;
  if (g < N){ int o = off[g] + bsum[g >> 10]; off[g] = o; cur[g] = o; }
}
__global__ void scatter_perm_k(const int* __restrict__ src, const int* __restrict__ tgt,
                               int* __restrict__ cur, int* __restrict__ perm, int E){
  int e = blockIdx.x*blockDim.x + threadIdx.x;
  if (e < E){ int p = atomicAdd(&cur[tgt[e]], 1); perm[p] = src[e]; }
}

// ---------------- weight prep (fp32, tiny) ----------------
// WsWct[i] = W_self[i] @ W_comb[i][0:64]; bsWct[i] = b_self[i] @ W_comb[i][0:64]
__global__ void matW_k(const float* __restrict__ W_self, const float* __restrict__ W_comb,
                       const float* __restrict__ b_self,
                       float* __restrict__ WsWct, float* __restrict__ bsWct){
  __shared__ float sWs[4096], sWc[4096];
  const int i = blockIdx.x, t = threadIdx.x;
  for (int idx = t; idx < 4096; idx += 256){
    sWs[idx] = W_self[i*4096 + idx];
    sWc[idx] = W_comb[i*8192 + idx];   // rows 0..63
  }
  __syncthreads();
  for (int idx = t; idx < 4096; idx += 256){
    int a = idx >> 6, c = idx & 63;
    float s = 0.f;
    for (int k = 0; k < 64; ++k) s += sWs[a*64 + k] * sWc[k*64 + c];
    WsWct[i*4096 + idx] = s;
  }
  if (t < 64){
    float s = 0.f;
    for (int k = 0; k < 64; ++k) s += b_self[i*64 + k] * sWc[k*64 + t];
    bsWct[i*64 + t] = s;
  }
}
__global__ void buildComb_k(const float* __restrict__ W_self, const float* __restrict__ W_comb,
                            const float* __restrict__ b_self, const float* __restrict__ b_comb,
                            const float* __restrict__ Z_comb,
                            const float* __restrict__ WsWct, const float* __restrict__ bsWct,
                            float* __restrict__ W1eff, float* __restrict__ W2eff,
                            float* __restrict__ beff){
  const int i = blockIdx.x, t = threadIdx.x;
  const float zc0 = Z_comb[i*2], zc1 = Z_comb[i*2+1];
  for (int idx = t; idx < 4096; idx += blockDim.x){
    int k = idx >> 6, c = idx & 63;
    W1eff[i*4096 + idx] = zc0*W_self[i*4096 + idx] + zc1*WsWct[i*4096 + idx];
    W2eff[i*4096 + idx] = (k == c ? zc0 : 0.f) + zc1*W_comb[i*8192 + (64 + k)*64 + c];
  }
  if (t < 64)
    beff[i*64 + t] = zc0*b_self[i*64 + t] + zc1*(bsWct[i*64 + t] + b_comb[i*64 + t]);
}
__global__ void buildLc_k(const float* __restrict__ W_lc, const float* __restrict__ b_lc,
                          const float* __restrict__ Z_lc,
                          float* __restrict__ Wlceff, float* __restrict__ blceff){
  const int i = blockIdx.x, t = threadIdx.x;
  const float z0 = Z_lc[i*3], z1 = Z_lc[i*3+1], z2 = Z_lc[i*3+2];
  for (int idx = t; idx < 8192; idx += blockDim.x){
    int k = idx >> 6, c = idx & 63;
    float idv = (k < 64) ? (k == c ? z1 : 0.f) : ((k - 64) == c ? (z0 + z1) : 0.f);
    Wlceff[i*8192 + idx] = z2*W_lc[i*8192 + idx] + idv;
  }
  if (t < 64) blceff[i*64 + t] = z2*b_lc[i*64 + t];
}
__global__ void buildLagg_k(const float* __restrict__ W_lagg, const float* __restrict__ b_lagg,
                            const float* __restrict__ Z_lagg,
                            float* __restrict__ Wle, float* __restrict__ ble){
  const int t = threadIdx.x;
  const float zg0 = Z_lagg[0], zg2 = Z_lagg[2];
  for (int idx = t; idx < 16384; idx += blockDim.x){
    int k = idx >> 6, c = idx & 63;
    Wle[idx] = zg2*W_lagg[idx] + ((k >= 192 && (k - 192) == c) ? zg0 : 0.f);
  }
  if (t < 64) ble[t] = zg2*b_lagg[t];
}

// ---------------- pack fp32 [K][64] -> bf16 MFMA B-fragment layout ----------------
struct PackJobs {
  const float* src[15];
  u16* dst[15];
  int nkb[15];
};
__global__ void pack_all_k(PackJobs pj){
  const int job = blockIdx.x >> 3, kb = blockIdx.x & 7;
  if (kb >= pj.nkb[job]) return;
  const int t = threadIdx.x, cb = t >> 6, lane = t & 63;
  const float* S = pj.src[job];
  u16* D = pj.dst[job] + (((kb*4 + cb)*64 + lane) << 3);
  const int kbase = kb*32 + ((lane >> 4) << 3), c = cb*16 + (lane & 15);
#pragma unroll
  for (int j = 0; j < 8; ++j) D[j] = f2bf(S[(kbase + j)*64 + c]);
}

// ---------------- GEMM: single bf16 A [N][64], K=64 ----------------
template<bool RELU, bool OUT32>
__global__ __launch_bounds__(256) void gemm1_k(const u16* __restrict__ A,
    const u16* __restrict__ Wf, const float* __restrict__ bias,
    void* __restrict__ out, int N){
  const int lane = threadIdx.x & 63, w = threadIdx.x >> 6;
  const int R = blockIdx.x*64 + w*16;
  bfrag wf[2][4];
#pragma unroll
  for (int kb = 0; kb < 2; ++kb)
#pragma unroll
    for (int cb = 0; cb < 4; ++cb) wf[kb][cb] = ldW(Wf, kb, cb, lane);
  float bv[4];
#pragma unroll
  for (int cb = 0; cb < 4; ++cb) bv[cb] = bias[cb*16 + (lane & 15)];
  const long ra = (R + (lane & 15) < N) ? (R + (lane & 15)) : (N - 1);
  f4v acc[4] = {f4v{0,0,0,0}, f4v{0,0,0,0}, f4v{0,0,0,0}, f4v{0,0,0,0}};
#pragma unroll
  for (int kb = 0; kb < 2; ++kb){
    bfrag a = ldA(A, ra, kb*32, lane);
#pragma unroll
    for (int cb = 0; cb < 4; ++cb) acc[cb] = MFMA(a, wf[kb][cb], acc[cb]);
  }
  const int rbase = R + ((lane >> 4) << 2), cl = lane & 15;
#pragma unroll
  for (int cb = 0; cb < 4; ++cb)
#pragma unroll
    for (int j = 0; j < 4; ++j){
      int r = rbase + j;
      if (r < N){
        float v = acc[cb][j] + bv[cb];
        if (RELU) v = fmaxf(v, 0.f);
        if (OUT32) ((float*)out)[(size_t)r*64 + cb*16 + cl] = v;
        else       ((u16*)out)[(size_t)r*64 + cb*16 + cl] = f2bf(v);
      }
    }
}

// ---------------- GEMM: two bf16 A's (K=128 concat), plain epilogue (layer-connect) ----------------
__global__ __launch_bounds__(256) void gemm2_k(const u16* __restrict__ A1,
    const u16* __restrict__ A2, const u16* __restrict__ Wf,
    const float* __restrict__ bias, u16* __restrict__ out, int N){
  const int lane = threadIdx.x & 63, w = threadIdx.x >> 6;
  const int R = blockIdx.x*64 + w*16;
  bfrag wf[4][4];
#pragma unroll
  for (int kb = 0; kb < 4; ++kb)
#pragma unroll
    for (int cb = 0; cb < 4; ++cb) wf[kb][cb] = ldW(Wf, kb, cb, lane);
  float bv[4];
#pragma unroll
  for (int cb = 0; cb < 4; ++cb) bv[cb] = bias[cb*16 + (lane & 15)];
  const long ra = (R + (lane & 15) < N) ? (R + (lane & 15)) : (N - 1);
  f4v acc[4] = {f4v{0,0,0,0}, f4v{0,0,0,0}, f4v{0,0,0,0}, f4v{0,0,0,0}};
#pragma unroll
  for (int kb = 0; kb < 4; ++kb){
    bfrag a = (kb < 2) ? ldA(A1, ra, kb*32, lane) : ldA(A2, ra, (kb-2)*32, lane);
#pragma unroll
    for (int cb = 0; cb < 4; ++cb) acc[cb] = MFMA(a, wf[kb][cb], acc[cb]);
  }
  const int rbase = R + ((lane >> 4) << 2), cl = lane & 15;
#pragma unroll
  for (int cb = 0; cb < 4; ++cb)
#pragma unroll
    for (int j = 0; j < 4; ++j){
      int r = rbase + j;
      if (r < N) out[(size_t)r*64 + cb*16 + cl] = f2bf(acc[cb][j] + bv[cb]);
    }
}

// ---------------- GEMM combine: h = x@W1eff + xn@W2eff + beff; act mix; layernorm ----------------
__global__ __launch_bounds__(256) void gemmC_k(const u16* __restrict__ A1,
    const u16* __restrict__ A2, const u16* __restrict__ Wf1, const u16* __restrict__ Wf2,
    const float* __restrict__ beff, const float* __restrict__ lng, const float* __restrict__ lnb,
    const float* __restrict__ Zact, const float* __restrict__ prelu,
    u16* __restrict__ out, int N){
  const int lane = threadIdx.x & 63, w = threadIdx.x >> 6;
  const int R = blockIdx.x*64 + w*16;
  bfrag wf1[2][4], wf2[2][4];
#pragma unroll
  for (int kb = 0; kb < 2; ++kb)
#pragma unroll
    for (int cb = 0; cb < 4; ++cb){ wf1[kb][cb] = ldW(Wf1, kb, cb, lane); wf2[kb][cb] = ldW(Wf2, kb, cb, lane); }
  float bv[4], lgv[4], lbv[4];
#pragma unroll
  for (int cb = 0; cb < 4; ++cb){
    int c = cb*16 + (lane & 15);
    bv[cb] = beff[c]; lgv[cb] = lng[c]; lbv[cb] = lnb[c];
  }
  const float zt0 = Zact[0], zt1 = Zact[1], pw = prelu[0];
  const long ra = (R + (lane & 15) < N) ? (R + (lane & 15)) : (N - 1);
  f4v acc[4] = {f4v{0,0,0,0}, f4v{0,0,0,0}, f4v{0,0,0,0}, f4v{0,0,0,0}};
#pragma unroll
  for (int kb = 0; kb < 2; ++kb){
    bfrag a = ldA(A1, ra, kb*32, lane);
#pragma unroll
    for (int cb = 0; cb < 4; ++cb) acc[cb] = MFMA(a, wf1[kb][cb], acc[cb]);
  }
#pragma unroll
  for (int kb = 0; kb < 2; ++kb){
    bfrag a = ldA(A2, ra, kb*32, lane);
#pragma unroll
    for (int cb = 0; cb < 4; ++cb) acc[cb] = MFMA(a, wf2[kb][cb], acc[cb]);
  }
  // bias + act mixture
#pragma unroll
  for (int cb = 0; cb < 4; ++cb)
#pragma unroll
    for (int j = 0; j < 4; ++j){
      float v = acc[cb][j] + bv[cb];
      v = zt0*fmaxf(v, 0.f) + zt1*((v > 0.f) ? v : pw*v);
      acc[cb][j] = v;
    }
  // layernorm over 64 cols (16 lanes x 4 cb per row), then store
  const int rbase = R + ((lane >> 4) << 2), cl = lane & 15;
#pragma unroll
  for (int j = 0; j < 4; ++j){
    float s = acc[0][j] + acc[1][j] + acc[2][j] + acc[3][j];
    s += __shfl_xor(s, 1, 64); s += __shfl_xor(s, 2, 64);
    s += __shfl_xor(s, 4, 64); s += __shfl_xor(s, 8, 64);
    float mu = s * 0.015625f;
    float d0 = acc[0][j]-mu, d1 = acc[1][j]-mu, d2 = acc[2][j]-mu, d3 = acc[3][j]-mu;
    float q = d0*d0 + d1*d1 + d2*d2 + d3*d3;
    q += __shfl_xor(q, 1, 64); q += __shfl_xor(q, 2, 64);
    q += __shfl_xor(q, 4, 64); q += __shfl_xor(q, 8, 64);
    float sd = rsqrtf(q * 0.015625f + 1e-5f);
    int r = rbase + j;
    if (r < N){
      out[(size_t)r*64 +  0 + cl] = f2bf(d0*sd*lgv[0] + lbv[0]);
      out[(size_t)r*64 + 16 + cl] = f2bf(d1*sd*lgv[1] + lbv[1]);
      out[(size_t)r*64 + 32 + cl] = f2bf(d2*sd*lgv[2] + lbv[2]);
      out[(size_t)r*64 + 48 + cl] = f2bf(d3*sd*lgv[3] + lbv[3]);
    }
  }
}

// ---------------- GEMM layer-agg: K=256 over 4 embs + zg1*max ----------------
__global__ __launch_bounds__(256) void gemmL_k(const u16* __restrict__ e0,
    const u16* __restrict__ e1, const u16* __restrict__ e2, const u16* __restrict__ e3,
    const u16* __restrict__ Wf, const float* __restrict__ bias,
    const u16* __restrict__ mbuf, const float* __restrict__ Z_lagg,
    u16* __restrict__ out, int N){
  const int lane = threadIdx.x & 63, w = threadIdx.x >> 6;
  const int R = blockIdx.x*64 + w*16;
  const u16* Ab[4] = {e0, e1, e2, e3};
  bfrag wf[8][4];
#pragma unroll
  for (int kb = 0; kb < 8; ++kb)
#pragma unroll
    for (int cb = 0; cb < 4; ++cb) wf[kb][cb] = ldW(Wf, kb, cb, lane);
  float bv[4];
#pragma unroll
  for (int cb = 0; cb < 4; ++cb) bv[cb] = bias[cb*16 + (lane & 15)];
  const float zg1 = Z_lagg[1];
  const long ra = (R + (lane & 15) < N) ? (R + (lane & 15)) : (N - 1);
  f4v acc[4] = {f4v{0,0,0,0}, f4v{0,0,0,0}, f4v{0,0,0,0}, f4v{0,0,0,0}};
#pragma unroll
  for (int kb = 0; kb < 8; ++kb){
    bfrag a = ldA(Ab[kb >> 1], ra, (kb & 1)*32, lane);
#pragma unroll
    for (int cb = 0; cb < 4; ++cb) acc[cb] = MFMA(a, wf[kb][cb], acc[cb]);
  }
  const int rbase = R + ((lane >> 4) << 2), cl = lane & 15;
#pragma unroll
  for (int cb = 0; cb < 4; ++cb)
#pragma unroll
    for (int j = 0; j < 4; ++j){
      int r = rbase + j;
      if (r < N){
        float v = acc[cb][j] + bv[cb] + zg1*bf2f(mbuf[(size_t)r*64 + cb*16 + cl]);
        out[(size_t)r*64 + cb*16 + cl] = f2bf(v);
      }
    }
}

// ---------------- GEMM pre: fp32 A [N][128] -> bf16 inline, K=128 ----------------
__global__ __launch_bounds__(256) void gemmP_k(const float* __restrict__ X,
    const u16* __restrict__ Wf, const float* __restrict__ bias,
    u16* __restrict__ out, int N){
  const int lane = threadIdx.x & 63, w = threadIdx.x >> 6;
  const int R = blockIdx.x*64 + w*16;
  bfrag wf[4][4];
#pragma unroll
  for (int kb = 0; kb < 4; ++kb)
#pragma unroll
    for (int cb = 0; cb < 4; ++cb) wf[kb][cb] = ldW(Wf, kb, cb, lane);
  float bv[4];
#pragma unroll
  for (int cb = 0; cb < 4; ++cb) bv[cb] = bias[cb*16 + (lane & 15)];
  const long ra = (R + (lane & 15) < N) ? (R + (lane & 15)) : (N - 1);
  f4v acc[4] = {f4v{0,0,0,0}, f4v{0,0,0,0}, f4v{0,0,0,0}, f4v{0,0,0,0}};
#pragma unroll
  for (int kb = 0; kb < 4; ++kb){
    const float* ap = X + ra*128 + kb*32 + ((lane >> 4) << 3);
    float4 q0 = *reinterpret_cast<const float4*>(ap);
    float4 q1 = *reinterpret_cast<const float4*>(ap + 4);
    bfrag a;
    a[0] = (short)f2bf(q0.x); a[1] = (short)f2bf(q0.y);
    a[2] = (short)f2bf(q0.z); a[3] = (short)f2bf(q0.w);
    a[4] = (short)f2bf(q1.x); a[5] = (short)f2bf(q1.y);
    a[6] = (short)f2bf(q1.z); a[7] = (short)f2bf(q1.w);
#pragma unroll
    for (int cb = 0; cb < 4; ++cb) acc[cb] = MFMA(a, wf[kb][cb], acc[cb]);
  }
  const int rbase = R + ((lane >> 4) << 2), cl = lane & 15;
#pragma unroll
  for (int cb = 0; cb < 4; ++cb)
#pragma unroll
    for (int j = 0; j < 4; ++j){
      int r = rbase + j;
      if (r < N) out[(size_t)r*64 + cb*16 + cl] = f2bf(acc[cb][j] + bv[cb]);
    }
}

// ---------------- neighbor aggregate: bf16 rows, 2 cols/lane, 2 nbrs per wave-instr ----------------
__global__ __launch_bounds__(256) void gather_k(const u16* __restrict__ xnl,
    const int* __restrict__ off, const int* __restrict__ cnt, const int* __restrict__ perm,
    const float* __restrict__ Z_agg, int layer, u16* __restrict__ xn, int N){
  const int lane = threadIdx.x & 63, w = threadIdx.x >> 6;
  const int r = blockIdx.x*4 + w;
  if (r >= N) return;
  const float za0 = Z_agg[layer*3+0], za1 = Z_agg[layer*3+1], za2 = Z_agg[layer*3+2];
  const int e0 = off[r], deg = cnt[r];
  const int half = lane >> 5, colb = lane & 31;
  float s0 = 0.f, s1 = 0.f, m0 = -3.402823466e38f, m1 = -3.402823466e38f;
  for (int base = 0; base < deg; base += 64){
    int nrem = deg - base; if (nrem > 64) nrem = 64;
    int pe = (lane < nrem) ? perm[e0 + base + lane] : 0;
#pragma unroll 4
    for (int j = 0; j < nrem; j += 2){
      int idx = j + half;
      int s = __shfl(pe, idx, 64);
      if (idx < nrem){
        u32 u = *reinterpret_cast<const u32*>(xnl + (size_t)s*64 + colb*2);
        float a = bf2f((u16)(u & 0xffffu)), b = bf2f((u16)(u >> 16));
        s0 += a; s1 += b;
        m0 = fmaxf(m0, a); m1 = fmaxf(m1, b);
      }
    }
  }
  s0 += __shfl_xor(s0, 32, 64); s1 += __shfl_xor(s1, 32, 64);
  m0 = fmaxf(m0, __shfl_xor(m0, 32, 64)); m1 = fmaxf(m1, __shfl_xor(m1, 32, 64));
  if (lane < 32){
    float inv = 1.f / fmaxf((float)deg, 1.f);
    float v0 = za0*s0 + za1*s0*inv + za2*((deg > 0) ? m0 : 0.f);
    float v1 = za0*s1 + za1*s1*inv + za2*((deg > 0) ? m1 : 0.f);
    u32 o = (u32)f2bf(v0) | (((u32)f2bf(v1)) << 16);
    *reinterpret_cast<u32*>(xn + (size_t)r*64 + colb*2) = o;
  }
}

// ---------------- elementwise max of 4 embs ----------------
__global__ void maxe_k(const u16* __restrict__ e0, const u16* __restrict__ e1,
                       const u16* __restrict__ e2, const u16* __restrict__ e3,
                       u16* __restrict__ m, long total8){
  long i = (long)blockIdx.x*blockDim.x + threadIdx.x;
  if (i >= total8) return;
  const uint4 a = reinterpret_cast<const uint4*>(e0)[i];
  const uint4 b = reinterpret_cast<const uint4*>(e1)[i];
  const uint4 c = reinterpret_cast<const uint4*>(e2)[i];
  const uint4 d = reinterpret_cast<const uint4*>(e3)[i];
  uint4 o;
  const u32 av[4] = {a.x, a.y, a.z, a.w}, bv[4] = {b.x, b.y, b.z, b.w};
  const u32 cv[4] = {c.x, c.y, c.z, c.w}, dv[4] = {d.x, d.y, d.z, d.w};
  u32 ov[4];
#pragma unroll
  for (int t = 0; t < 4; ++t){
    float lo = fmaxf(fmaxf(bf2f((u16)(av[t] & 0xffffu)), bf2f((u16)(bv[t] & 0xffffu))),
                     fmaxf(bf2f((u16)(cv[t] & 0xffffu)), bf2f((u16)(dv[t] & 0xffffu))));
    float hi = fmaxf(fmaxf(bf2f((u16)(av[t] >> 16)), bf2f((u16)(bv[t] >> 16))),
                     fmaxf(bf2f((u16)(cv[t] >> 16)), bf2f((u16)(dv[t] >> 16))));
    ov[t] = (u32)f2bf(lo) | (((u32)f2bf(hi)) << 16);
  }
  o.x = ov[0]; o.y = ov[1]; o.z = ov[2]; o.w = ov[3];
  reinterpret_cast<uint4*>(m)[i] = o;
}

extern "C" void kernel_launch(void* const* d_in, const int* in_sizes, int n_in,
                              void* d_out, int out_size, void* d_ws, size_t ws_size,
                              hipStream_t stream){
  const float* x      = (const float*)d_in[0];
  const int*   ei     = (const int*)  d_in[1];
  const float* W_pre  = (const float*)d_in[2];
  const float* b_pre  = (const float*)d_in[3];
  const float* W_self = (const float*)d_in[4];
  const float* b_self = (const float*)d_in[5];
  const float* W_nbr  = (const float*)d_in[6];
  const float* b_nbr  = (const float*)d_in[7];
  const float* W_comb = (const float*)d_in[8];
  const float* b_comb = (const float*)d_in[9];
  const float* W_lc   = (const float*)d_in[10];
  const float* b_lc   = (const float*)d_in[11];
  const float* ln_g   = (const float*)d_in[12];
  const float* ln_b   = (const float*)d_in[13];
  const float* prelu  = (const float*)d_in[14];
  const float* W_lagg = (const float*)d_in[15];
  const float* b_lagg = (const float*)d_in[16];
  const float* W_ff1  = (const float*)d_in[17];
  const float* b_ff1  = (const float*)d_in[18];
  const float* W_ff2  = (const float*)d_in[19];
  const float* b_ff2  = (const float*)d_in[20];
  const float* Z_agg  = (const float*)d_in[21];
  const float* Z_comb = (const float*)d_in[22];
  const float* Z_act  = (const float*)d_in[23];
  const float* Z_lc   = (const float*)d_in[24];
  const float* Z_lagg = (const float*)d_in[25];

  const int N = in_sizes[0] / 128;
  const int E = in_sizes[1] / 2;
  const int* src = ei;
  const int* tgt = ei + E;

  char* p = (char*)d_ws;
  auto carve = [&](size_t bytes)->void*{
    void* q = (void*)p;
    p += (bytes + 255) & ~(size_t)255;
    return q;
  };
  // CSR
  int* cnt_i = (int*)carve((size_t)N*4);
  int* off   = (int*)carve((size_t)N*4);
  int* cur   = (int*)carve((size_t)N*4);
  int* bsum  = (int*)carve(4096*4);
  int* perm  = (int*)carve((size_t)E*4);
  // fp32 effective weights
  float* WsWct = (float*)carve(3*4096*4);
  float* bsWct = (float*)carve(3*64*4);
  float* W1eff = (float*)carve(3*4096*4);
  float* W2eff = (float*)carve(3*4096*4);
  float* beff  = (float*)carve(3*64*4);
  float* Wlceff= (float*)carve(2*8192*4);
  float* blceff= (float*)carve(2*64*4);
  float* Wle   = (float*)carve(16384*4);
  float* ble   = (float*)carve(64*4);
  // packed bf16 fragments
  u16* pWpre = (u16*)carve(8192*2);
  u16* pWnbr = (u16*)carve(3*4096*2);
  u16* pW1   = (u16*)carve(3*4096*2);
  u16* pW2   = (u16*)carve(3*4096*2);
  u16* pWlc  = (u16*)carve(2*8192*2);
  u16* pWlagg= (u16*)carve(16384*2);
  u16* pWff1 = (u16*)carve(4096*2);
  u16* pWff2 = (u16*)carve(4096*2);
  // bf16 activations [N][64]
  const size_t AB = (size_t)N*64*2;
  u16* emb0 = (u16*)carve(AB);
  u16* emb1 = (u16*)carve(AB);
  u16* emb2 = (u16*)carve(AB);
  u16* emb3 = (u16*)carve(AB);
  u16* xbuf = (u16*)carve(AB);
  u16* xnl  = (u16*)carve(AB);
  u16* xn   = (u16*)carve(AB);
  u16* mixb = (u16*)carve(AB);
  u16* tbuf = (u16*)carve(AB);
  u16* mbuf = (u16*)carve(AB);

  // ---- CSR build ----
  hipMemsetAsync(cnt_i, 0, (size_t)N*4, stream);
  count_k<<<DIV_UP(E,256),256,0,stream>>>(tgt, cnt_i, E);
  const int nb = DIV_UP(N, SCAN_B);
  blockscan_k<<<nb,SCAN_B,0,stream>>>(cnt_i, off, bsum, N);
  scan2_k<<<1,SCAN_B,0,stream>>>(bsum, nb);
  addback_k<<<DIV_UP(N,256),256,0,stream>>>(off, bsum, cur, N);
  scatter_perm_k<<<DIV_UP(E,256),256,0,stream>>>(src, tgt, cur, perm, E);

  // ---- weight prep ----
  matW_k<<<3,256,0,stream>>>(W_self, W_comb, b_self, WsWct, bsWct);
  buildComb_k<<<3,1024,0,stream>>>(W_self, W_comb, b_self, b_comb, Z_comb,
                                   WsWct, bsWct, W1eff, W2eff, beff);
  buildLc_k<<<2,1024,0,stream>>>(W_lc, b_lc, Z_lc, Wlceff, blceff);
  buildLagg_k<<<1,1024,0,stream>>>(W_lagg, b_lagg, Z_lagg, Wle, ble);

  PackJobs pj;
  pj.src[0] = W_pre;  pj.dst[0] = pWpre;  pj.nkb[0] = 4;
  for (int i = 0; i < 3; ++i){
    pj.src[1+i] = W_nbr + i*4096; pj.dst[1+i] = pWnbr + i*4096; pj.nkb[1+i] = 2;
    pj.src[4+i] = W1eff + i*4096; pj.dst[4+i] = pW1   + i*4096; pj.nkb[4+i] = 2;
    pj.src[7+i] = W2eff + i*4096; pj.dst[7+i] = pW2   + i*4096; pj.nkb[7+i] = 2;
  }
  pj.src[10] = Wlceff;        pj.dst[10] = pWlc;        pj.nkb[10] = 4;
  pj.src[11] = Wlceff + 8192; pj.dst[11] = pWlc + 8192; pj.nkb[11] = 4;
  pj.src[12] = Wle;   pj.dst[12] = pWlagg; pj.nkb[12] = 8;
  pj.src[13] = W_ff1; pj.dst[13] = pWff1;  pj.nkb[13] = 2;
  pj.src[14] = W_ff2; pj.dst[14] = pWff2;  pj.nkb[14] = 2;
  pack_all_k<<<15*8,256,0,stream>>>(pj);

  const int G64 = DIV_UP(N, 64);

  // ---- preprocess ----
  gemmP_k<<<G64,256,0,stream>>>(x, pWpre, b_pre, emb0, N);

  // ---- layers ----
  u16* embs[4] = {emb0, emb1, emb2, emb3};
  const u16* xin = emb0;
  for (int i = 0; i < 3; ++i){
    gemm1_k<false,false><<<G64,256,0,stream>>>(xin, pWnbr + i*4096, b_nbr + i*64, xnl, N);
    gather_k<<<DIV_UP(N,4),256,0,stream>>>(xnl, off, cnt_i, perm, Z_agg, i, xn, N);
    gemmC_k<<<G64,256,0,stream>>>(xin, xn, pW1 + i*4096, pW2 + i*4096,
                                  beff + i*64, ln_g + i*64, ln_b + i*64,
                                  Z_act + i*2, prelu + i, embs[i+1], N);
    if (i < 2){
      gemm2_k<<<G64,256,0,stream>>>(embs[i], embs[i+1], pWlc + i*8192,
                                    blceff + i*64, xbuf, N);
      xin = xbuf;
    }
  }

  // ---- layer agg + head ----
  maxe_k<<<DIV_UP(N*64/8,256),256,0,stream>>>(emb0, emb1, emb2, emb3, mbuf, (long)N*64/8);
  gemmL_k<<<G64,256,0,stream>>>(emb0, emb1, emb2, emb3, pWlagg, ble, mbuf, Z_lagg, mixb, N);
  gemm1_k<true,false><<<G64,256,0,stream>>>(mixb, pWff1, b_ff1, tbuf, N);
  gemm1_k<false,true><<<G64,256,0,stream>>>(tbuf, pWff2, b_ff2, d_out, N);
}

// Round 3
// 515.897 us; speedup vs baseline: 3.6466x; 1.1765x over previous
//
#include <hip/hip_runtime.h>

typedef unsigned short u16;
typedef unsigned int u32;
using bfrag = __attribute__((ext_vector_type(8))) short;
using f4v   = __attribute__((ext_vector_type(4))) float;

#define DIV_UP(a,b) (((a)+(b)-1)/(b))
#define SCAN_B 1024
#define NCH 8
#define MFMA(a,b,c) __builtin_amdgcn_mfma_f32_16x16x32_bf16(a,b,c,0,0,0)

__device__ inline u16 f2bf(float f){
  union { float f; u32 u; } v; v.f = f;
  u32 u = v.u;
  return (u16)((u + 0x7fffu + ((u >> 16) & 1u)) >> 16);
}
__device__ inline float bf2f(u16 h){
  union { u32 u; float f; } v; v.u = ((u32)h) << 16;
  return v.f;
}
__device__ inline bfrag ldA(const u16* A, long r, int koff, int lane){
  return *reinterpret_cast<const bfrag*>(A + r*64 + koff + ((lane>>4)<<3));
}
__device__ inline bfrag ldW(const u16* Wf, int kb, int cb, int lane){
  return *reinterpret_cast<const bfrag*>(Wf + (((kb*4+cb)*64 + lane)<<3));
}

// --- per-wave 16x64 C-tile -> A-fragment transpose via swizzled LDS (no barrier) ---
__device__ inline void xpose_store(u16* sT, int lane, const f4v (&acc)[4]){
  const int cl = lane & 15, g = lane >> 4;
#pragma unroll
  for (int j = 0; j < 4; ++j){
    const int lr = g*4 + j;
#pragma unroll
    for (int cb = 0; cb < 4; ++cb){
      const int colblk = cb*2 + (cl >> 3);
      const int gr = colblk ^ (lr & 7);
      sT[lr*64 + gr*8 + (cl & 7)] = f2bf(acc[cb][j]);
    }
  }
}
__device__ inline bfrag xpose_load(const u16* sT, int lane, int kb){
  const int row = lane & 15, colblk = kb*4 + (lane >> 4);
  const int gr = colblk ^ (row & 7);
  return *reinterpret_cast<const bfrag*>(sT + row*64 + gr*8);
}

// ---------------- CSR build (chunked by target range: kills write amplification) ----------------
__global__ void count_chunk_k(const int* __restrict__ tgt, int* __restrict__ cnt,
                              int E, int chunkN){
  const int tid = blockIdx.x*blockDim.x + threadIdx.x;
  const int stride = gridDim.x*blockDim.x;
  const int E4 = E >> 2;
  for (int c = 0; c < NCH; ++c){
    const int lo = c*chunkN, hi = lo + chunkN;
    for (int i = tid; i < E4; i += stride){
      int4 t4 = reinterpret_cast<const int4*>(tgt)[i];
      if (t4.x >= lo && t4.x < hi) atomicAdd(&cnt[t4.x], 1);
      if (t4.y >= lo && t4.y < hi) atomicAdd(&cnt[t4.y], 1);
      if (t4.z >= lo && t4.z < hi) atomicAdd(&cnt[t4.z], 1);
      if (t4.w >= lo && t4.w < hi) atomicAdd(&cnt[t4.w], 1);
    }
    for (int i = (E4 << 2) + tid; i < E; i += stride){
      int t = tgt[i];
      if (t >= lo && t < hi) atomicAdd(&cnt[t], 1);
    }
  }
}
__global__ void scatter_chunk_k(const int* __restrict__ src, const int* __restrict__ tgt,
                                int* __restrict__ cur, int* __restrict__ perm,
                                int E, int chunkN){
  const int tid = blockIdx.x*blockDim.x + threadIdx.x;
  const int stride = gridDim.x*blockDim.x;
  const int E4 = E >> 2;
  for (int c = 0; c < NCH; ++c){
    const int lo = c*chunkN, hi = lo + chunkN;
    for (int i = tid; i < E4; i += stride){
      int4 t4 = reinterpret_cast<const int4*>(tgt)[i];
      int4 s4 = reinterpret_cast<const int4*>(src)[i];
      if (t4.x >= lo && t4.x < hi){ int p = atomicAdd(&cur[t4.x], 1); perm[p] = s4.x; }
      if (t4.y >= lo && t4.y < hi){ int p = atomicAdd(&cur[t4.y], 1); perm[p] = s4.y; }
      if (t4.z >= lo && t4.z < hi){ int p = atomicAdd(&cur[t4.z], 1); perm[p] = s4.z; }
      if (t4.w >= lo && t4.w < hi){ int p = atomicAdd(&cur[t4.w], 1); perm[p] = s4.w; }
    }
    for (int i = (E4 << 2) + tid; i < E; i += stride){
      int t = tgt[i];
      if (t >= lo && t < hi){ int p = atomicAdd(&cur[t], 1); perm[p] = src[i]; }
    }
  }
}
__global__ void blockscan_k(const int* __restrict__ cnt, int* __restrict__ off,
                            int* __restrict__ bsum, int N){
  __shared__ int sd[SCAN_B];
  int t = threadIdx.x; int g = blockIdx.x*SCAN_B + t;
  int v = (g < N) ? cnt[g] : 0;
  sd[t] = v; __syncthreads();
  for (int o = 1; o < SCAN_B; o <<= 1){
    int add = (t >= o) ? sd[t-o] : 0;
    __syncthreads(); sd[t] += add; __syncthreads();
  }
  if (g < N) off[g] = sd[t] - v;
  if (t == SCAN_B-1) bsum[blockIdx.x] = sd[t];
}
__global__ void scan2_k(int* __restrict__ bsum, int nb){
  __shared__ int sd[SCAN_B];
  int t = threadIdx.x;
  int v = (t < nb) ? bsum[t] : 0;
  sd[t] = v; __syncthreads();
  for (int o = 1; o < SCAN_B; o <<= 1){
    int add = (t >= o) ? sd[t-o] : 0;
    __syncthreads(); sd[t] += add; __syncthreads();
  }
  if (t < nb) bsum[t] = sd[t] - v;
}
__global__ void addback_k(int* __restrict__ off, const int* __restrict__ bsum,
                          int* __restrict__ cur, int N){
  int g = blockIdx.x*blockDim.x + threadIdx.x;
  if (g < N){ int o = off[g] + bsum[g >> 10]; off[g] = o; cur[g] = o; }
}

// ---------------- weight prep (fp32, tiny) ----------------
__global__ void matW_k(const float* __restrict__ W_self, const float* __restrict__ W_comb,
                       const float* __restrict__ b_self,
                       float* __restrict__ WsWct, float* __restrict__ bsWct){
  __shared__ float sWs[4096], sWc[4096];
  const int i = blockIdx.x, t = threadIdx.x;
  for (int idx = t; idx < 4096; idx += 256){
    sWs[idx] = W_self[i*4096 + idx];
    sWc[idx] = W_comb[i*8192 + idx];
  }
  __syncthreads();
  for (int idx = t; idx < 4096; idx += 256){
    int a = idx >> 6, c = idx & 63;
    float s = 0.f;
    for (int k = 0; k < 64; ++k) s += sWs[a*64 + k] * sWc[k*64 + c];
    WsWct[i*4096 + idx] = s;
  }
  if (t < 64){
    float s = 0.f;
    for (int k = 0; k < 64; ++k) s += b_self[i*64 + k] * sWc[k*64 + t];
    bsWct[i*64 + t] = s;
  }
}
__global__ void buildComb_k(const float* __restrict__ W_self, const float* __restrict__ W_comb,
                            const float* __restrict__ b_self, const float* __restrict__ b_comb,
                            const float* __restrict__ Z_comb,
                            const float* __restrict__ WsWct, const float* __restrict__ bsWct,
                            float* __restrict__ W1eff, float* __restrict__ W2eff,
                            float* __restrict__ beff){
  const int i = blockIdx.x, t = threadIdx.x;
  const float zc0 = Z_comb[i*2], zc1 = Z_comb[i*2+1];
  for (int idx = t; idx < 4096; idx += blockDim.x){
    int k = idx >> 6, c = idx & 63;
    W1eff[i*4096 + idx] = zc0*W_self[i*4096 + idx] + zc1*WsWct[i*4096 + idx];
    W2eff[i*4096 + idx] = (k == c ? zc0 : 0.f) + zc1*W_comb[i*8192 + (64 + k)*64 + c];
  }
  if (t < 64)
    beff[i*64 + t] = zc0*b_self[i*64 + t] + zc1*(bsWct[i*64 + t] + b_comb[i*64 + t]);
}
__global__ void buildLc_k(const float* __restrict__ W_lc, const float* __restrict__ b_lc,
                          const float* __restrict__ Z_lc,
                          float* __restrict__ Wlceff, float* __restrict__ blceff){
  const int i = blockIdx.x, t = threadIdx.x;
  const float z0 = Z_lc[i*3], z1 = Z_lc[i*3+1], z2 = Z_lc[i*3+2];
  for (int idx = t; idx < 8192; idx += blockDim.x){
    int k = idx >> 6, c = idx & 63;
    float idv = (k < 64) ? (k == c ? z1 : 0.f) : ((k - 64) == c ? (z0 + z1) : 0.f);
    Wlceff[i*8192 + idx] = z2*W_lc[i*8192 + idx] + idv;
  }
  if (t < 64) blceff[i*64 + t] = z2*b_lc[i*64 + t];
}
__global__ void buildLagg_k(const float* __restrict__ W_lagg, const float* __restrict__ b_lagg,
                            const float* __restrict__ Z_lagg,
                            float* __restrict__ Wle, float* __restrict__ ble){
  const int t = threadIdx.x;
  const float zg0 = Z_lagg[0], zg2 = Z_lagg[2];
  for (int idx = t; idx < 16384; idx += blockDim.x){
    int k = idx >> 6, c = idx & 63;
    Wle[idx] = zg2*W_lagg[idx] + ((k >= 192 && (k - 192) == c) ? zg0 : 0.f);
  }
  if (t < 64) ble[t] = zg2*b_lagg[t];
}

// ---------------- pack fp32 [K][64] -> bf16 MFMA B-fragment layout ----------------
struct PackJobs {
  const float* src[15];
  u16* dst[15];
  int nkb[15];
};
__global__ void pack_all_k(PackJobs pj){
  const int job = blockIdx.x >> 3, kb = blockIdx.x & 7;
  if (kb >= pj.nkb[job]) return;
  const int t = threadIdx.x, cb = t >> 6, lane = t & 63;
  const float* S = pj.src[job];
  u16* D = pj.dst[job] + (((kb*4 + cb)*64 + lane) << 3);
  const int kbase = kb*32 + ((lane >> 4) << 3), c = cb*16 + (lane & 15);
#pragma unroll
  for (int j = 0; j < 8; ++j) D[j] = f2bf(S[(kbase + j)*64 + c]);
}

// ---------------- GEMM pre: fp32 A [N][128] -> emb0, fused xnl0 = emb0@Wnbr0 + bnbr0 ----------------
__global__ __launch_bounds__(256) void gemmP_k(const float* __restrict__ X,
    const u16* __restrict__ Wf, const float* __restrict__ bias,
    const u16* __restrict__ Wn, const float* __restrict__ bn,
    u16* __restrict__ out, u16* __restrict__ xnl, int N){
  __shared__ u16 sT[4][1024];
  const int lane = threadIdx.x & 63, w = threadIdx.x >> 6;
  const int R = blockIdx.x*64 + w*16;
  bfrag wf[4][4], wn[2][4];
#pragma unroll
  for (int kb = 0; kb < 4; ++kb)
#pragma unroll
    for (int cb = 0; cb < 4; ++cb) wf[kb][cb] = ldW(Wf, kb, cb, lane);
#pragma unroll
  for (int kb = 0; kb < 2; ++kb)
#pragma unroll
    for (int cb = 0; cb < 4; ++cb) wn[kb][cb] = ldW(Wn, kb, cb, lane);
  float bv[4], bnv[4];
#pragma unroll
  for (int cb = 0; cb < 4; ++cb){ bv[cb] = bias[cb*16 + (lane & 15)]; bnv[cb] = bn[cb*16 + (lane & 15)]; }
  const long ra = (R + (lane & 15) < N) ? (R + (lane & 15)) : (N - 1);
  f4v acc[4] = {f4v{0,0,0,0}, f4v{0,0,0,0}, f4v{0,0,0,0}, f4v{0,0,0,0}};
#pragma unroll
  for (int kb = 0; kb < 4; ++kb){
    const float* ap = X + ra*128 + kb*32 + ((lane >> 4) << 3);
    float4 q0 = *reinterpret_cast<const float4*>(ap);
    float4 q1 = *reinterpret_cast<const float4*>(ap + 4);
    bfrag a;
    a[0] = (short)f2bf(q0.x); a[1] = (short)f2bf(q0.y);
    a[2] = (short)f2bf(q0.z); a[3] = (short)f2bf(q0.w);
    a[4] = (short)f2bf(q1.x); a[5] = (short)f2bf(q1.y);
    a[6] = (short)f2bf(q1.z); a[7] = (short)f2bf(q1.w);
#pragma unroll
    for (int cb = 0; cb < 4; ++cb) acc[cb] = MFMA(a, wf[kb][cb], acc[cb]);
  }
#pragma unroll
  for (int cb = 0; cb < 4; ++cb)
#pragma unroll
    for (int j = 0; j < 4; ++j) acc[cb][j] += bv[cb];
  const int rbase = R + ((lane >> 4) << 2), cl = lane & 15;
#pragma unroll
  for (int cb = 0; cb < 4; ++cb)
#pragma unroll
    for (int j = 0; j < 4; ++j){
      int r = rbase + j;
      if (r < N) out[(size_t)r*64 + cb*16 + cl] = f2bf(acc[cb][j]);
    }
  // fused x_nl0
  xpose_store(sT[w], lane, acc);
  f4v ac2[4] = {f4v{0,0,0,0}, f4v{0,0,0,0}, f4v{0,0,0,0}, f4v{0,0,0,0}};
#pragma unroll
  for (int kb = 0; kb < 2; ++kb){
    bfrag a = xpose_load(sT[w], lane, kb);
#pragma unroll
    for (int cb = 0; cb < 4; ++cb) ac2[cb] = MFMA(a, wn[kb][cb], ac2[cb]);
  }
#pragma unroll
  for (int cb = 0; cb < 4; ++cb)
#pragma unroll
    for (int j = 0; j < 4; ++j){
      int r = rbase + j;
      if (r < N) xnl[(size_t)r*64 + cb*16 + cl] = f2bf(ac2[cb][j] + bnv[cb]);
    }
}

// ---------------- GEMM combine: h = x@W1eff + xn@W2eff + beff; act mix; layernorm ----------------
__global__ __launch_bounds__(256) void gemmC_k(const u16* __restrict__ A1,
    const u16* __restrict__ A2, const u16* __restrict__ Wf1, const u16* __restrict__ Wf2,
    const float* __restrict__ beff, const float* __restrict__ lng, const float* __restrict__ lnb,
    const float* __restrict__ Zact, const float* __restrict__ prelu,
    u16* __restrict__ out, int N){
  const int lane = threadIdx.x & 63, w = threadIdx.x >> 6;
  const int R = blockIdx.x*64 + w*16;
  bfrag wf1[2][4], wf2[2][4];
#pragma unroll
  for (int kb = 0; kb < 2; ++kb)
#pragma unroll
    for (int cb = 0; cb < 4; ++cb){ wf1[kb][cb] = ldW(Wf1, kb, cb, lane); wf2[kb][cb] = ldW(Wf2, kb, cb, lane); }
  float bv[4], lgv[4], lbv[4];
#pragma unroll
  for (int cb = 0; cb < 4; ++cb){
    int c = cb*16 + (lane & 15);
    bv[cb] = beff[c]; lgv[cb] = lng[c]; lbv[cb] = lnb[c];
  }
  const float zt0 = Zact[0], zt1 = Zact[1], pw = prelu[0];
  const long ra = (R + (lane & 15) < N) ? (R + (lane & 15)) : (N - 1);
  f4v acc[4] = {f4v{0,0,0,0}, f4v{0,0,0,0}, f4v{0,0,0,0}, f4v{0,0,0,0}};
#pragma unroll
  for (int kb = 0; kb < 2; ++kb){
    bfrag a = ldA(A1, ra, kb*32, lane);
#pragma unroll
    for (int cb = 0; cb < 4; ++cb) acc[cb] = MFMA(a, wf1[kb][cb], acc[cb]);
  }
#pragma unroll
  for (int kb = 0; kb < 2; ++kb){
    bfrag a = ldA(A2, ra, kb*32, lane);
#pragma unroll
    for (int cb = 0; cb < 4; ++cb) acc[cb] = MFMA(a, wf2[kb][cb], acc[cb]);
  }
#pragma unroll
  for (int cb = 0; cb < 4; ++cb)
#pragma unroll
    for (int j = 0; j < 4; ++j){
      float v = acc[cb][j] + bv[cb];
      v = zt0*fmaxf(v, 0.f) + zt1*((v > 0.f) ? v : pw*v);
      acc[cb][j] = v;
    }
  const int rbase = R + ((lane >> 4) << 2), cl = lane & 15;
#pragma unroll
  for (int j = 0; j < 4; ++j){
    float s = acc[0][j] + acc[1][j] + acc[2][j] + acc[3][j];
    s += __shfl_xor(s, 1, 64); s += __shfl_xor(s, 2, 64);
    s += __shfl_xor(s, 4, 64); s += __shfl_xor(s, 8, 64);
    float mu = s * 0.015625f;
    float d0 = acc[0][j]-mu, d1 = acc[1][j]-mu, d2 = acc[2][j]-mu, d3 = acc[3][j]-mu;
    float q = d0*d0 + d1*d1 + d2*d2 + d3*d3;
    q += __shfl_xor(q, 1, 64); q += __shfl_xor(q, 2, 64);
    q += __shfl_xor(q, 4, 64); q += __shfl_xor(q, 8, 64);
    float sd = rsqrtf(q * 0.015625f + 1e-5f);
    int r = rbase + j;
    if (r < N){
      out[(size_t)r*64 +  0 + cl] = f2bf(d0*sd*lgv[0] + lbv[0]);
      out[(size_t)r*64 + 16 + cl] = f2bf(d1*sd*lgv[1] + lbv[1]);
      out[(size_t)r*64 + 32 + cl] = f2bf(d2*sd*lgv[2] + lbv[2]);
      out[(size_t)r*64 + 48 + cl] = f2bf(d3*sd*lgv[3] + lbv[3]);
    }
  }
}

// ---------------- layer-connect (K=128 concat) fused with next layer's x_nl ----------------
__global__ __launch_bounds__(256) void lc_k(const u16* __restrict__ A1,
    const u16* __restrict__ A2, const u16* __restrict__ Wf,
    const float* __restrict__ bias, const u16* __restrict__ Wn,
    const float* __restrict__ bn, u16* __restrict__ out, u16* __restrict__ xnl, int N){
  __shared__ u16 sT[4][1024];
  const int lane = threadIdx.x & 63, w = threadIdx.x >> 6;
  const int R = blockIdx.x*64 + w*16;
  bfrag wf[4][4], wn[2][4];
#pragma unroll
  for (int kb = 0; kb < 4; ++kb)
#pragma unroll
    for (int cb = 0; cb < 4; ++cb) wf[kb][cb] = ldW(Wf, kb, cb, lane);
#pragma unroll
  for (int kb = 0; kb < 2; ++kb)
#pragma unroll
    for (int cb = 0; cb < 4; ++cb) wn[kb][cb] = ldW(Wn, kb, cb, lane);
  float bv[4], bnv[4];
#pragma unroll
  for (int cb = 0; cb < 4; ++cb){ bv[cb] = bias[cb*16 + (lane & 15)]; bnv[cb] = bn[cb*16 + (lane & 15)]; }
  const long ra = (R + (lane & 15) < N) ? (R + (lane & 15)) : (N - 1);
  f4v acc[4] = {f4v{0,0,0,0}, f4v{0,0,0,0}, f4v{0,0,0,0}, f4v{0,0,0,0}};
#pragma unroll
  for (int kb = 0; kb < 4; ++kb){
    bfrag a = (kb < 2) ? ldA(A1, ra, kb*32, lane) : ldA(A2, ra, (kb-2)*32, lane);
#pragma unroll
    for (int cb = 0; cb < 4; ++cb) acc[cb] = MFMA(a, wf[kb][cb], acc[cb]);
  }
#pragma unroll
  for (int cb = 0; cb < 4; ++cb)
#pragma unroll
    for (int j = 0; j < 4; ++j) acc[cb][j] += bv[cb];
  const int rbase = R + ((lane >> 4) << 2), cl = lane & 15;
#pragma unroll
  for (int cb = 0; cb < 4; ++cb)
#pragma unroll
    for (int j = 0; j < 4; ++j){
      int r = rbase + j;
      if (r < N) out[(size_t)r*64 + cb*16 + cl] = f2bf(acc[cb][j]);
    }
  // fused x_nl for next layer
  xpose_store(sT[w], lane, acc);
  f4v ac2[4] = {f4v{0,0,0,0}, f4v{0,0,0,0}, f4v{0,0,0,0}, f4v{0,0,0,0}};
#pragma unroll
  for (int kb = 0; kb < 2; ++kb){
    bfrag a = xpose_load(sT[w], lane, kb);
#pragma unroll
    for (int cb = 0; cb < 4; ++cb) ac2[cb] = MFMA(a, wn[kb][cb], ac2[cb]);
  }
#pragma unroll
  for (int cb = 0; cb < 4; ++cb)
#pragma unroll
    for (int j = 0; j < 4; ++j){
      int r = rbase + j;
      if (r < N) xnl[(size_t)r*64 + cb*16 + cl] = f2bf(ac2[cb][j] + bnv[cb]);
    }
}

// ---------------- GEMM layer-agg: K=256 over 4 embs + zg1*max ----------------
__global__ __launch_bounds__(256) void gemmL_k(const u16* __restrict__ e0,
    const u16* __restrict__ e1, const u16* __restrict__ e2, const u16* __restrict__ e3,
    const u16* __restrict__ Wf, const float* __restrict__ bias,
    const u16* __restrict__ mbuf, const float* __restrict__ Z_lagg,
    u16* __restrict__ out, int N){
  const int lane = threadIdx.x & 63, w = threadIdx.x >> 6;
  const int R = blockIdx.x*64 + w*16;
  const u16* Ab[4] = {e0, e1, e2, e3};
  bfrag wf[8][4];
#pragma unroll
  for (int kb = 0; kb < 8; ++kb)
#pragma unroll
    for (int cb = 0; cb < 4; ++cb) wf[kb][cb] = ldW(Wf, kb, cb, lane);
  float bv[4];
#pragma unroll
  for (int cb = 0; cb < 4; ++cb) bv[cb] = bias[cb*16 + (lane & 15)];
  const float zg1 = Z_lagg[1];
  const long ra = (R + (lane & 15) < N) ? (R + (lane & 15)) : (N - 1);
  f4v acc[4] = {f4v{0,0,0,0}, f4v{0,0,0,0}, f4v{0,0,0,0}, f4v{0,0,0,0}};
#pragma unroll
  for (int kb = 0; kb < 8; ++kb){
    bfrag a = ldA(Ab[kb >> 1], ra, (kb & 1)*32, lane);
#pragma unroll
    for (int cb = 0; cb < 4; ++cb) acc[cb] = MFMA(a, wf[kb][cb], acc[cb]);
  }
  const int rbase = R + ((lane >> 4) << 2), cl = lane & 15;
#pragma unroll
  for (int cb = 0; cb < 4; ++cb)
#pragma unroll
    for (int j = 0; j < 4; ++j){
      int r = rbase + j;
      if (r < N){
        float v = acc[cb][j] + bv[cb] + zg1*bf2f(mbuf[(size_t)r*64 + cb*16 + cl]);
        out[(size_t)r*64 + cb*16 + cl] = f2bf(v);
      }
    }
}

// ---------------- fused feed-forward head: relu(mix@W1+b1)@W2 + b2 -> fp32 out ----------------
__global__ __launch_bounds__(256) void ff12_k(const u16* __restrict__ A,
    const u16* __restrict__ Wf1, const float* __restrict__ b1,
    const u16* __restrict__ Wf2, const float* __restrict__ b2,
    float* __restrict__ out, int N){
  __shared__ u16 sT[4][1024];
  const int lane = threadIdx.x & 63, w = threadIdx.x >> 6;
  const int R = blockIdx.x*64 + w*16;
  bfrag wf1[2][4], wf2[2][4];
#pragma unroll
  for (int kb = 0; kb < 2; ++kb)
#pragma unroll
    for (int cb = 0; cb < 4; ++cb){ wf1[kb][cb] = ldW(Wf1, kb, cb, lane); wf2[kb][cb] = ldW(Wf2, kb, cb, lane); }
  float bv1[4], bv2[4];
#pragma unroll
  for (int cb = 0; cb < 4; ++cb){ bv1[cb] = b1[cb*16 + (lane & 15)]; bv2[cb] = b2[cb*16 + (lane & 15)]; }
  const long ra = (R + (lane & 15) < N) ? (R + (lane & 15)) : (N - 1);
  f4v acc[4] = {f4v{0,0,0,0}, f4v{0,0,0,0}, f4v{0,0,0,0}, f4v{0,0,0,0}};
#pragma unroll
  for (int kb = 0; kb < 2; ++kb){
    bfrag a = ldA(A, ra, kb*32, lane);
#pragma unroll
    for (int cb = 0; cb < 4; ++cb) acc[cb] = MFMA(a, wf1[kb][cb], acc[cb]);
  }
#pragma unroll
  for (int cb = 0; cb < 4; ++cb)
#pragma unroll
    for (int j = 0; j < 4; ++j) acc[cb][j] = fmaxf(acc[cb][j] + bv1[cb], 0.f);
  xpose_store(sT[w], lane, acc);
  f4v ac2[4] = {f4v{0,0,0,0}, f4v{0,0,0,0}, f4v{0,0,0,0}, f4v{0,0,0,0}};
#pragma unroll
  for (int kb = 0; kb < 2; ++kb){
    bfrag a = xpose_load(sT[w], lane, kb);
#pragma unroll
    for (int cb = 0; cb < 4; ++cb) ac2[cb] = MFMA(a, wf2[kb][cb], ac2[cb]);
  }
  const int rbase = R + ((lane >> 4) << 2), cl = lane & 15;
#pragma unroll
  for (int cb = 0; cb < 4; ++cb)
#pragma unroll
    for (int j = 0; j < 4; ++j){
      int r = rbase + j;
      if (r < N) out[(size_t)r*64 + cb*16 + cl] = ac2[cb][j] + bv2[cb];
    }
}

// ---------------- neighbor aggregate: 4 neighbors in flight, 8B loads ----------------
__global__ __launch_bounds__(256) void gather_k(const u16* __restrict__ xnl,
    const int* __restrict__ off, const int* __restrict__ cnt, const int* __restrict__ perm,
    const float* __restrict__ Z_agg, int layer, u16* __restrict__ xn, int N){
  const int lane = threadIdx.x & 63, w = threadIdx.x >> 6;
  const int r = blockIdx.x*4 + w;
  if (r >= N) return;
  const float za0 = Z_agg[layer*3+0], za1 = Z_agg[layer*3+1], za2 = Z_agg[layer*3+2];
  const int e0 = off[r], deg = cnt[r];
  const int q = lane & 15, g = lane >> 4;   // g = neighbor slot, q = channel quarter
  const float NI = -3.402823466e38f;
  float s0 = 0.f, s1 = 0.f, s2 = 0.f, s3 = 0.f;
  float m0 = NI, m1 = NI, m2 = NI, m3 = NI;
  for (int base = 0; base < deg; base += 64){
    int nrem = deg - base; if (nrem > 64) nrem = 64;
    int pe = (lane < nrem) ? perm[e0 + base + lane] : 0;
    for (int j = 0; j < nrem; j += 4){
      int idx = j + g;
      int s = __shfl(pe, idx, 64);
      if (idx < nrem){
        ushort4 u = *reinterpret_cast<const ushort4*>(xnl + (size_t)s*64 + q*4);
        float a = bf2f(u.x), b = bf2f(u.y), c = bf2f(u.z), d = bf2f(u.w);
        s0 += a; s1 += b; s2 += c; s3 += d;
        m0 = fmaxf(m0, a); m1 = fmaxf(m1, b); m2 = fmaxf(m2, c); m3 = fmaxf(m3, d);
      }
    }
  }
  s0 += __shfl_xor(s0, 16, 64); s1 += __shfl_xor(s1, 16, 64);
  s2 += __shfl_xor(s2, 16, 64); s3 += __shfl_xor(s3, 16, 64);
  s0 += __shfl_xor(s0, 32, 64); s1 += __shfl_xor(s1, 32, 64);
  s2 += __shfl_xor(s2, 32, 64); s3 += __shfl_xor(s3, 32, 64);
  m0 = fmaxf(m0, __shfl_xor(m0, 16, 64)); m1 = fmaxf(m1, __shfl_xor(m1, 16, 64));
  m2 = fmaxf(m2, __shfl_xor(m2, 16, 64)); m3 = fmaxf(m3, __shfl_xor(m3, 16, 64));
  m0 = fmaxf(m0, __shfl_xor(m0, 32, 64)); m1 = fmaxf(m1, __shfl_xor(m1, 32, 64));
  m2 = fmaxf(m2, __shfl_xor(m2, 32, 64)); m3 = fmaxf(m3, __shfl_xor(m3, 32, 64));
  if (g == 0){
    float inv = 1.f / fmaxf((float)deg, 1.f);
    float gz = (deg > 0) ? 1.f : 0.f;
    ushort4 o;
    o.x = f2bf(za0*s0 + za1*s0*inv + za2*gz*m0);
    o.y = f2bf(za0*s1 + za1*s1*inv + za2*gz*m1);
    o.z = f2bf(za0*s2 + za1*s2*inv + za2*gz*m2);
    o.w = f2bf(za0*s3 + za1*s3*inv + za2*gz*m3);
    *reinterpret_cast<ushort4*>(xn + (size_t)r*64 + q*4) = o;
  }
}

// ---------------- elementwise max of 4 embs ----------------
__global__ void maxe_k(const u16* __restrict__ e0, const u16* __restrict__ e1,
                       const u16* __restrict__ e2, const u16* __restrict__ e3,
                       u16* __restrict__ m, long total8){
  long i = (long)blockIdx.x*blockDim.x + threadIdx.x;
  if (i >= total8) return;
  const uint4 a = reinterpret_cast<const uint4*>(e0)[i];
  const uint4 b = reinterpret_cast<const uint4*>(e1)[i];
  const uint4 c = reinterpret_cast<const uint4*>(e2)[i];
  const uint4 d = reinterpret_cast<const uint4*>(e3)[i];
  const u32 av[4] = {a.x, a.y, a.z, a.w}, bv[4] = {b.x, b.y, b.z, b.w};
  const u32 cv[4] = {c.x, c.y, c.z, c.w}, dv[4] = {d.x, d.y, d.z, d.w};
  u32 ov[4];
#pragma unroll
  for (int t = 0; t < 4; ++t){
    float lo = fmaxf(fmaxf(bf2f((u16)(av[t] & 0xffffu)), bf2f((u16)(bv[t] & 0xffffu))),
                     fmaxf(bf2f((u16)(cv[t] & 0xffffu)), bf2f((u16)(dv[t] & 0xffffu))));
    float hi = fmaxf(fmaxf(bf2f((u16)(av[t] >> 16)), bf2f((u16)(bv[t] >> 16))),
                     fmaxf(bf2f((u16)(cv[t] >> 16)), bf2f((u16)(dv[t] >> 16))));
    ov[t] = (u32)f2bf(lo) | (((u32)f2bf(hi)) << 16);
  }
  uint4 o; o.x = ov[0]; o.y = ov[1]; o.z = ov[2]; o.w = ov[3];
  reinterpret_cast<uint4*>(m)[i] = o;
}

extern "C" void kernel_launch(void* const* d_in, const int* in_sizes, int n_in,
                              void* d_out, int out_size, void* d_ws, size_t ws_size,
                              hipStream_t stream){
  const float* x      = (const float*)d_in[0];
  const int*   ei     = (const int*)  d_in[1];
  const float* W_pre  = (const float*)d_in[2];
  const float* b_pre  = (const float*)d_in[3];
  const float* W_self = (const float*)d_in[4];
  const float* b_self = (const float*)d_in[5];
  const float* W_nbr  = (const float*)d_in[6];
  const float* b_nbr  = (const float*)d_in[7];
  const float* W_comb = (const float*)d_in[8];
  const float* b_comb = (const float*)d_in[9];
  const float* W_lc   = (const float*)d_in[10];
  const float* b_lc   = (const float*)d_in[11];
  const float* ln_g   = (const float*)d_in[12];
  const float* ln_b   = (const float*)d_in[13];
  const float* prelu  = (const float*)d_in[14];
  const float* W_lagg = (const float*)d_in[15];
  const float* b_lagg = (const float*)d_in[16];
  const float* W_ff1  = (const float*)d_in[17];
  const float* b_ff1  = (const float*)d_in[18];
  const float* W_ff2  = (const float*)d_in[19];
  const float* b_ff2  = (const float*)d_in[20];
  const float* Z_agg  = (const float*)d_in[21];
  const float* Z_comb = (const float*)d_in[22];
  const float* Z_act  = (const float*)d_in[23];
  const float* Z_lc   = (const float*)d_in[24];
  const float* Z_lagg = (const float*)d_in[25];

  const int N = in_sizes[0] / 128;
  const int E = in_sizes[1] / 2;
  const int* src = ei;
  const int* tgt = ei + E;

  char* p = (char*)d_ws;
  auto carve = [&](size_t bytes)->void*{
    void* q = (void*)p;
    p += (bytes + 255) & ~(size_t)255;
    return q;
  };
  int* cnt_i = (int*)carve((size_t)N*4);
  int* off   = (int*)carve((size_t)N*4);
  int* cur   = (int*)carve((size_t)N*4);
  int* bsum  = (int*)carve(4096*4);
  int* perm  = (int*)carve((size_t)E*4);
  float* WsWct = (float*)carve(3*4096*4);
  float* bsWct = (float*)carve(3*64*4);
  float* W1eff = (float*)carve(3*4096*4);
  float* W2eff = (float*)carve(3*4096*4);
  float* beff  = (float*)carve(3*64*4);
  float* Wlceff= (float*)carve(2*8192*4);
  float* blceff= (float*)carve(2*64*4);
  float* Wle   = (float*)carve(16384*4);
  float* ble   = (float*)carve(64*4);
  u16* pWpre = (u16*)carve(8192*2);
  u16* pWnbr = (u16*)carve(3*4096*2);
  u16* pW1   = (u16*)carve(3*4096*2);
  u16* pW2   = (u16*)carve(3*4096*2);
  u16* pWlc  = (u16*)carve(2*8192*2);
  u16* pWlagg= (u16*)carve(16384*2);
  u16* pWff1 = (u16*)carve(4096*2);
  u16* pWff2 = (u16*)carve(4096*2);
  const size_t AB = (size_t)N*64*2;
  u16* emb0 = (u16*)carve(AB);
  u16* emb1 = (u16*)carve(AB);
  u16* emb2 = (u16*)carve(AB);
  u16* emb3 = (u16*)carve(AB);
  u16* xbuf = (u16*)carve(AB);
  u16* xnl  = (u16*)carve(AB);
  u16* xn   = (u16*)carve(AB);
  u16* mixb = (u16*)carve(AB);
  u16* mbuf = (u16*)carve(AB);

  const int chunkN = DIV_UP(N, NCH);

  // ---- CSR build (chunked; write regions stay L2-resident per chunk) ----
  hipMemsetAsync(cnt_i, 0, (size_t)N*4, stream);
  count_chunk_k<<<1024,256,0,stream>>>(tgt, cnt_i, E, chunkN);
  const int nb = DIV_UP(N, SCAN_B);
  blockscan_k<<<nb,SCAN_B,0,stream>>>(cnt_i, off, bsum, N);
  scan2_k<<<1,SCAN_B,0,stream>>>(bsum, nb);
  addback_k<<<DIV_UP(N,256),256,0,stream>>>(off, bsum, cur, N);
  scatter_chunk_k<<<1024,256,0,stream>>>(src, tgt, cur, perm, E, chunkN);

  // ---- weight prep ----
  matW_k<<<3,256,0,stream>>>(W_self, W_comb, b_self, WsWct, bsWct);
  buildComb_k<<<3,1024,0,stream>>>(W_self, W_comb, b_self, b_comb, Z_comb,
                                   WsWct, bsWct, W1eff, W2eff, beff);
  buildLc_k<<<2,1024,0,stream>>>(W_lc, b_lc, Z_lc, Wlceff, blceff);
  buildLagg_k<<<1,1024,0,stream>>>(W_lagg, b_lagg, Z_lagg, Wle, ble);

  PackJobs pj;
  pj.src[0] = W_pre;  pj.dst[0] = pWpre;  pj.nkb[0] = 4;
  for (int i = 0; i < 3; ++i){
    pj.src[1+i] = W_nbr + i*4096; pj.dst[1+i] = pWnbr + i*4096; pj.nkb[1+i] = 2;
    pj.src[4+i] = W1eff + i*4096; pj.dst[4+i] = pW1   + i*4096; pj.nkb[4+i] = 2;
    pj.src[7+i] = W2eff + i*4096; pj.dst[7+i] = pW2   + i*4096; pj.nkb[7+i] = 2;
  }
  pj.src[10] = Wlceff;        pj.dst[10] = pWlc;        pj.nkb[10] = 4;
  pj.src[11] = Wlceff + 8192; pj.dst[11] = pWlc + 8192; pj.nkb[11] = 4;
  pj.src[12] = Wle;   pj.dst[12] = pWlagg; pj.nkb[12] = 8;
  pj.src[13] = W_ff1; pj.dst[13] = pWff1;  pj.nkb[13] = 2;
  pj.src[14] = W_ff2; pj.dst[14] = pWff2;  pj.nkb[14] = 2;
  pack_all_k<<<15*8,256,0,stream>>>(pj);

  const int G64 = DIV_UP(N, 64);

  // ---- preprocess (+ fused x_nl layer 0) ----
  gemmP_k<<<G64,256,0,stream>>>(x, pWpre, b_pre, pWnbr, b_nbr, emb0, xnl, N);

  // ---- layers ----
  u16* embs[4] = {emb0, emb1, emb2, emb3};
  const u16* xin = emb0;
  for (int i = 0; i < 3; ++i){
    gather_k<<<DIV_UP(N,4),256,0,stream>>>(xnl, off, cnt_i, perm, Z_agg, i, xn, N);
    gemmC_k<<<G64,256,0,stream>>>(xin, xn, pW1 + i*4096, pW2 + i*4096,
                                  beff + i*64, ln_g + i*64, ln_b + i*64,
                                  Z_act + i*2, prelu + i, embs[i+1], N);
    if (i < 2){
      lc_k<<<G64,256,0,stream>>>(embs[i], embs[i+1], pWlc + i*8192, blceff + i*64,
                                 pWnbr + (i+1)*4096, b_nbr + (i+1)*64, xbuf, xnl, N);
      xin = xbuf;
    }
  }

  // ---- layer agg + head ----
  maxe_k<<<DIV_UP(N*64/8,256),256,0,stream>>>(emb0, emb1, emb2, emb3, mbuf, (long)N*64/8);
  gemmL_k<<<G64,256,0,stream>>>(emb0, emb1, emb2, emb3, pWlagg, ble, mbuf, Z_lagg, mixb, N);
  ff12_k<<<G64,256,0,stream>>>(mixb, pWff1, b_ff1, pWff2, b_ff2, (float*)d_out, N);
}

// Round 4
// 456.863 us; speedup vs baseline: 4.1177x; 1.1292x over previous
//
#include <hip/hip_runtime.h>

typedef unsigned short u16;
typedef unsigned int u32;
using bfrag = __attribute__((ext_vector_type(8))) short;
using f4v   = __attribute__((ext_vector_type(4))) float;

#define DIV_UP(a,b) (((a)+(b)-1)/(b))
#define SCAN_B 1024
#define NCH 8
#define MFMA(a,b,c) __builtin_amdgcn_mfma_f32_16x16x32_bf16(a,b,c,0,0,0)

__device__ inline u16 f2bf(float f){
  union { float f; u32 u; } v; v.f = f;
  u32 u = v.u;
  return (u16)((u + 0x7fffu + ((u >> 16) & 1u)) >> 16);
}
__device__ inline float bf2f(u16 h){
  union { u32 u; float f; } v; v.u = ((u32)h) << 16;
  return v.f;
}
__device__ inline bfrag ldA(const u16* A, long r, int koff, int lane){
  return *reinterpret_cast<const bfrag*>(A + r*64 + koff + ((lane>>4)<<3));
}
__device__ inline bfrag ldW(const u16* Wf, int kb, int cb, int lane){
  return *reinterpret_cast<const bfrag*>(Wf + (((kb*4+cb)*64 + lane)<<3));
}

// --- per-wave 16x64 C-tile -> A-fragment transpose via swizzled LDS (no barrier) ---
__device__ inline void xpose_store(u16* sT, int lane, const f4v (&acc)[4]){
  const int cl = lane & 15, g = lane >> 4;
#pragma unroll
  for (int j = 0; j < 4; ++j){
    const int lr = g*4 + j;
#pragma unroll
    for (int cb = 0; cb < 4; ++cb){
      const int colblk = cb*2 + (cl >> 3);
      const int gr = colblk ^ (lr & 7);
      sT[lr*64 + gr*8 + (cl & 7)] = f2bf(acc[cb][j]);
    }
  }
}
__device__ inline bfrag xpose_load(const u16* sT, int lane, int kb){
  const int row = lane & 15, colblk = kb*4 + (lane >> 4);
  const int gr = colblk ^ (row & 7);
  return *reinterpret_cast<const bfrag*>(sT + row*64 + gr*8);
}

// ---------------- CSR build: XCD-owned chunks (blockIdx.x & 7 == XCD id) ----------------
// All atomics/writes for chunk c come from one XCD's L2 -> lines accumulate locally,
// evict once. Wrong XCD mapping only costs locality, never correctness.
__global__ void count_x_k(const int* __restrict__ tgt, int* __restrict__ cnt,
                          int E, int chunkN, int N){
  const int c = blockIdx.x & 7;
  const int lo = c*chunkN, hi = (lo + chunkN < N) ? lo + chunkN : N;
  const int tid = (blockIdx.x >> 3)*blockDim.x + threadIdx.x;
  const int stride = (gridDim.x >> 3)*blockDim.x;
  const int E4 = E >> 2;
  for (int i = tid; i < E4; i += stride){
    int4 t4 = reinterpret_cast<const int4*>(tgt)[i];
    if (t4.x >= lo && t4.x < hi) atomicAdd(&cnt[t4.x], 1);
    if (t4.y >= lo && t4.y < hi) atomicAdd(&cnt[t4.y], 1);
    if (t4.z >= lo && t4.z < hi) atomicAdd(&cnt[t4.z], 1);
    if (t4.w >= lo && t4.w < hi) atomicAdd(&cnt[t4.w], 1);
  }
  for (int i = (E4 << 2) + tid; i < E; i += stride){
    int t = tgt[i];
    if (t >= lo && t < hi) atomicAdd(&cnt[t], 1);
  }
}
__global__ void scatter_x_k(const int* __restrict__ src, const int* __restrict__ tgt,
                            int* __restrict__ cur, int* __restrict__ perm,
                            int E, int chunkN, int N){
  const int c = blockIdx.x & 7;
  const int lo = c*chunkN, hi = (lo + chunkN < N) ? lo + chunkN : N;
  const int tid = (blockIdx.x >> 3)*blockDim.x + threadIdx.x;
  const int stride = (gridDim.x >> 3)*blockDim.x;
  const int E4 = E >> 2;
  for (int i = tid; i < E4; i += stride){
    int4 t4 = reinterpret_cast<const int4*>(tgt)[i];
    int4 s4 = reinterpret_cast<const int4*>(src)[i];
    if (t4.x >= lo && t4.x < hi){ int p = atomicAdd(&cur[t4.x], 1); perm[p] = s4.x; }
    if (t4.y >= lo && t4.y < hi){ int p = atomicAdd(&cur[t4.y], 1); perm[p] = s4.y; }
    if (t4.z >= lo && t4.z < hi){ int p = atomicAdd(&cur[t4.z], 1); perm[p] = s4.z; }
    if (t4.w >= lo && t4.w < hi){ int p = atomicAdd(&cur[t4.w], 1); perm[p] = s4.w; }
  }
  for (int i = (E4 << 2) + tid; i < E; i += stride){
    int t = tgt[i];
    if (t >= lo && t < hi){ int p = atomicAdd(&cur[t], 1); perm[p] = src[i]; }
  }
}
__global__ void blockscan_k(const int* __restrict__ cnt, int* __restrict__ off,
                            int* __restrict__ bsum, int N){
  __shared__ int sd[SCAN_B];
  int t = threadIdx.x; int g = blockIdx.x*SCAN_B + t;
  int v = (g < N) ? cnt[g] : 0;
  sd[t] = v; __syncthreads();
  for (int o = 1; o < SCAN_B; o <<= 1){
    int add = (t >= o) ? sd[t-o] : 0;
    __syncthreads(); sd[t] += add; __syncthreads();
  }
  if (g < N) off[g] = sd[t] - v;
  if (t == SCAN_B-1) bsum[blockIdx.x] = sd[t];
}
__global__ void scan2_k(int* __restrict__ bsum, int nb){
  __shared__ int sd[SCAN_B];
  int t = threadIdx.x;
  int v = (t < nb) ? bsum[t] : 0;
  sd[t] = v; __syncthreads();
  for (int o = 1; o < SCAN_B; o <<= 1){
    int add = (t >= o) ? sd[t-o] : 0;
    __syncthreads(); sd[t] += add; __syncthreads();
  }
  if (t < nb) bsum[t] = sd[t] - v;
}
__global__ void addback_k(int* __restrict__ off, const int* __restrict__ bsum,
                          int* __restrict__ cur, int N){
  int g = blockIdx.x*blockDim.x + threadIdx.x;
  if (g < N){ int o = off[g] + bsum[g >> 10]; off[g] = o; cur[g] = o; }
}

// ---------------- weight prep: one block per output row (195x64) ----------------
__global__ void matW_k(const float* __restrict__ W_self, const float* __restrict__ W_comb,
                       const float* __restrict__ b_self,
                       float* __restrict__ WsWct, float* __restrict__ bsWct){
  const int b = blockIdx.x;            // 3 layers * 65 rows
  const int i = b / 65, r = b % 65;
  const int c = threadIdx.x;           // 64
  const float* Wc = W_comb + i*8192;   // rows 0..63 (top half)
  float s = 0.f;
  if (r < 64){
    const float* a = W_self + i*4096 + r*64;
#pragma unroll 8
    for (int k = 0; k < 64; ++k) s += a[k] * Wc[k*64 + c];
    WsWct[i*4096 + r*64 + c] = s;
  } else {
    const float* a = b_self + i*64;
#pragma unroll 8
    for (int k = 0; k < 64; ++k) s += a[k] * Wc[k*64 + c];
    bsWct[i*64 + c] = s;
  }
}

// ---------------- all effective-weight builds in one grid-strided kernel ----------------
__global__ void buildAll_k(const float* __restrict__ W_self, const float* __restrict__ W_comb,
    const float* __restrict__ b_self, const float* __restrict__ b_comb,
    const float* __restrict__ Z_comb, const float* __restrict__ WsWct,
    const float* __restrict__ bsWct,
    const float* __restrict__ W_lc, const float* __restrict__ b_lc,
    const float* __restrict__ Z_lc,
    const float* __restrict__ W_lagg, const float* __restrict__ b_lagg,
    const float* __restrict__ Z_lagg,
    float* __restrict__ W1eff, float* __restrict__ W2eff, float* __restrict__ beff,
    float* __restrict__ Wlceff, float* __restrict__ blceff,
    float* __restrict__ Wle, float* __restrict__ ble){
  int idx = blockIdx.x*blockDim.x + threadIdx.x;
  if (idx < 12288){
    int i = idx >> 12, rem = idx & 4095, k = rem >> 6, c = rem & 63;
    float zc0 = Z_comb[i*2], zc1 = Z_comb[i*2+1];
    W1eff[idx] = zc0*W_self[idx] + zc1*WsWct[idx];
    W2eff[idx] = (k == c ? zc0 : 0.f) + zc1*W_comb[i*8192 + (64 + k)*64 + c];
    return;
  }
  idx -= 12288;
  if (idx < 16384){
    int i = idx >> 13, rem = idx & 8191, k = rem >> 6, c = rem & 63;
    float z0 = Z_lc[i*3], z1 = Z_lc[i*3+1], z2 = Z_lc[i*3+2];
    float idv = (k < 64) ? (k == c ? z1 : 0.f) : ((k - 64) == c ? (z0 + z1) : 0.f);
    Wlceff[idx] = z2*W_lc[idx] + idv;
    return;
  }
  idx -= 16384;
  if (idx < 16384){
    int k = idx >> 6, c = idx & 63;
    Wle[idx] = Z_lagg[2]*W_lagg[idx] + ((k >= 192 && (k - 192) == c) ? Z_lagg[0] : 0.f);
    return;
  }
  idx -= 16384;
  if (idx < 192){
    int i = idx >> 6;
    float zc0 = Z_comb[i*2], zc1 = Z_comb[i*2+1];
    beff[idx] = zc0*b_self[idx] + zc1*(bsWct[idx] + b_comb[idx]);
    return;
  }
  idx -= 192;
  if (idx < 128){
    int i = idx >> 6;
    blceff[idx] = Z_lc[i*3+2]*b_lc[idx];
    return;
  }
  idx -= 128;
  if (idx < 64) ble[idx] = Z_lagg[2]*b_lagg[idx];
}

// ---------------- pack fp32 [K][64] -> bf16 MFMA B-fragment layout ----------------
struct PackJobs {
  const float* src[15];
  u16* dst[15];
  int nkb[15];
};
__global__ void pack_all_k(PackJobs pj){
  const int job = blockIdx.x >> 3, kb = blockIdx.x & 7;
  if (kb >= pj.nkb[job]) return;
  const int t = threadIdx.x, cb = t >> 6, lane = t & 63;
  const float* S = pj.src[job];
  u16* D = pj.dst[job] + (((kb*4 + cb)*64 + lane) << 3);
  const int kbase = kb*32 + ((lane >> 4) << 3), c = cb*16 + (lane & 15);
#pragma unroll
  for (int j = 0; j < 8; ++j) D[j] = f2bf(S[(kbase + j)*64 + c]);
}

// ---------------- GEMM pre: fp32 A [N][128] -> emb0, fused xnl0 = emb0@Wnbr0 + bnbr0 ----------------
__global__ __launch_bounds__(256) void gemmP_k(const float* __restrict__ X,
    const u16* __restrict__ Wf, const float* __restrict__ bias,
    const u16* __restrict__ Wn, const float* __restrict__ bn,
    u16* __restrict__ out, u16* __restrict__ xnl, int N){
  __shared__ u16 sT[4][1024];
  const int lane = threadIdx.x & 63, w = threadIdx.x >> 6;
  const int R = blockIdx.x*64 + w*16;
  bfrag wf[4][4], wn[2][4];
#pragma unroll
  for (int kb = 0; kb < 4; ++kb)
#pragma unroll
    for (int cb = 0; cb < 4; ++cb) wf[kb][cb] = ldW(Wf, kb, cb, lane);
#pragma unroll
  for (int kb = 0; kb < 2; ++kb)
#pragma unroll
    for (int cb = 0; cb < 4; ++cb) wn[kb][cb] = ldW(Wn, kb, cb, lane);
  float bv[4], bnv[4];
#pragma unroll
  for (int cb = 0; cb < 4; ++cb){ bv[cb] = bias[cb*16 + (lane & 15)]; bnv[cb] = bn[cb*16 + (lane & 15)]; }
  const long ra = (R + (lane & 15) < N) ? (R + (lane & 15)) : (N - 1);
  f4v acc[4] = {f4v{0,0,0,0}, f4v{0,0,0,0}, f4v{0,0,0,0}, f4v{0,0,0,0}};
#pragma unroll
  for (int kb = 0; kb < 4; ++kb){
    const float* ap = X + ra*128 + kb*32 + ((lane >> 4) << 3);
    float4 q0 = *reinterpret_cast<const float4*>(ap);
    float4 q1 = *reinterpret_cast<const float4*>(ap + 4);
    bfrag a;
    a[0] = (short)f2bf(q0.x); a[1] = (short)f2bf(q0.y);
    a[2] = (short)f2bf(q0.z); a[3] = (short)f2bf(q0.w);
    a[4] = (short)f2bf(q1.x); a[5] = (short)f2bf(q1.y);
    a[6] = (short)f2bf(q1.z); a[7] = (short)f2bf(q1.w);
#pragma unroll
    for (int cb = 0; cb < 4; ++cb) acc[cb] = MFMA(a, wf[kb][cb], acc[cb]);
  }
#pragma unroll
  for (int cb = 0; cb < 4; ++cb)
#pragma unroll
    for (int j = 0; j < 4; ++j) acc[cb][j] += bv[cb];
  const int rbase = R + ((lane >> 4) << 2), cl = lane & 15;
#pragma unroll
  for (int cb = 0; cb < 4; ++cb)
#pragma unroll
    for (int j = 0; j < 4; ++j){
      int r = rbase + j;
      if (r < N) out[(size_t)r*64 + cb*16 + cl] = f2bf(acc[cb][j]);
    }
  // fused x_nl0
  xpose_store(sT[w], lane, acc);
  f4v ac2[4] = {f4v{0,0,0,0}, f4v{0,0,0,0}, f4v{0,0,0,0}, f4v{0,0,0,0}};
#pragma unroll
  for (int kb = 0; kb < 2; ++kb){
    bfrag a = xpose_load(sT[w], lane, kb);
#pragma unroll
    for (int cb = 0; cb < 4; ++cb) ac2[cb] = MFMA(a, wn[kb][cb], ac2[cb]);
  }
#pragma unroll
  for (int cb = 0; cb < 4; ++cb)
#pragma unroll
    for (int j = 0; j < 4; ++j){
      int r = rbase + j;
      if (r < N) xnl[(size_t)r*64 + cb*16 + cl] = f2bf(ac2[cb][j] + bnv[cb]);
    }
}

// ---------------- GEMM combine: h = x@W1eff + xn@W2eff + beff; act mix; layernorm ----------------
__global__ __launch_bounds__(256) void gemmC_k(const u16* __restrict__ A1,
    const u16* __restrict__ A2, const u16* __restrict__ Wf1, const u16* __restrict__ Wf2,
    const float* __restrict__ beff, const float* __restrict__ lng, const float* __restrict__ lnb,
    const float* __restrict__ Zact, const float* __restrict__ prelu,
    u16* __restrict__ out, int N){
  const int lane = threadIdx.x & 63, w = threadIdx.x >> 6;
  const int R = blockIdx.x*64 + w*16;
  bfrag wf1[2][4], wf2[2][4];
#pragma unroll
  for (int kb = 0; kb < 2; ++kb)
#pragma unroll
    for (int cb = 0; cb < 4; ++cb){ wf1[kb][cb] = ldW(Wf1, kb, cb, lane); wf2[kb][cb] = ldW(Wf2, kb, cb, lane); }
  float bv[4], lgv[4], lbv[4];
#pragma unroll
  for (int cb = 0; cb < 4; ++cb){
    int c = cb*16 + (lane & 15);
    bv[cb] = beff[c]; lgv[cb] = lng[c]; lbv[cb] = lnb[c];
  }
  const float zt0 = Zact[0], zt1 = Zact[1], pw = prelu[0];
  const long ra = (R + (lane & 15) < N) ? (R + (lane & 15)) : (N - 1);
  f4v acc[4] = {f4v{0,0,0,0}, f4v{0,0,0,0}, f4v{0,0,0,0}, f4v{0,0,0,0}};
#pragma unroll
  for (int kb = 0; kb < 2; ++kb){
    bfrag a = ldA(A1, ra, kb*32, lane);
#pragma unroll
    for (int cb = 0; cb < 4; ++cb) acc[cb] = MFMA(a, wf1[kb][cb], acc[cb]);
  }
#pragma unroll
  for (int kb = 0; kb < 2; ++kb){
    bfrag a = ldA(A2, ra, kb*32, lane);
#pragma unroll
    for (int cb = 0; cb < 4; ++cb) acc[cb] = MFMA(a, wf2[kb][cb], acc[cb]);
  }
#pragma unroll
  for (int cb = 0; cb < 4; ++cb)
#pragma unroll
    for (int j = 0; j < 4; ++j){
      float v = acc[cb][j] + bv[cb];
      v = zt0*fmaxf(v, 0.f) + zt1*((v > 0.f) ? v : pw*v);
      acc[cb][j] = v;
    }
  const int rbase = R + ((lane >> 4) << 2), cl = lane & 15;
#pragma unroll
  for (int j = 0; j < 4; ++j){
    float s = acc[0][j] + acc[1][j] + acc[2][j] + acc[3][j];
    s += __shfl_xor(s, 1, 64); s += __shfl_xor(s, 2, 64);
    s += __shfl_xor(s, 4, 64); s += __shfl_xor(s, 8, 64);
    float mu = s * 0.015625f;
    float d0 = acc[0][j]-mu, d1 = acc[1][j]-mu, d2 = acc[2][j]-mu, d3 = acc[3][j]-mu;
    float q = d0*d0 + d1*d1 + d2*d2 + d3*d3;
    q += __shfl_xor(q, 1, 64); q += __shfl_xor(q, 2, 64);
    q += __shfl_xor(q, 4, 64); q += __shfl_xor(q, 8, 64);
    float sd = rsqrtf(q * 0.015625f + 1e-5f);
    int r = rbase + j;
    if (r < N){
      out[(size_t)r*64 +  0 + cl] = f2bf(d0*sd*lgv[0] + lbv[0]);
      out[(size_t)r*64 + 16 + cl] = f2bf(d1*sd*lgv[1] + lbv[1]);
      out[(size_t)r*64 + 32 + cl] = f2bf(d2*sd*lgv[2] + lbv[2]);
      out[(size_t)r*64 + 48 + cl] = f2bf(d3*sd*lgv[3] + lbv[3]);
    }
  }
}

// ---------------- layer-connect (K=128 concat) fused with next layer's x_nl ----------------
__global__ __launch_bounds__(256) void lc_k(const u16* __restrict__ A1,
    const u16* __restrict__ A2, const u16* __restrict__ Wf,
    const float* __restrict__ bias, const u16* __restrict__ Wn,
    const float* __restrict__ bn, u16* __restrict__ out, u16* __restrict__ xnl, int N){
  __shared__ u16 sT[4][1024];
  const int lane = threadIdx.x & 63, w = threadIdx.x >> 6;
  const int R = blockIdx.x*64 + w*16;
  bfrag wf[4][4], wn[2][4];
#pragma unroll
  for (int kb = 0; kb < 4; ++kb)
#pragma unroll
    for (int cb = 0; cb < 4; ++cb) wf[kb][cb] = ldW(Wf, kb, cb, lane);
#pragma unroll
  for (int kb = 0; kb < 2; ++kb)
#pragma unroll
    for (int cb = 0; cb < 4; ++cb) wn[kb][cb] = ldW(Wn, kb, cb, lane);
  float bv[4], bnv[4];
#pragma unroll
  for (int cb = 0; cb < 4; ++cb){ bv[cb] = bias[cb*16 + (lane & 15)]; bnv[cb] = bn[cb*16 + (lane & 15)]; }
  const long ra = (R + (lane & 15) < N) ? (R + (lane & 15)) : (N - 1);
  f4v acc[4] = {f4v{0,0,0,0}, f4v{0,0,0,0}, f4v{0,0,0,0}, f4v{0,0,0,0}};
#pragma unroll
  for (int kb = 0; kb < 4; ++kb){
    bfrag a = (kb < 2) ? ldA(A1, ra, kb*32, lane) : ldA(A2, ra, (kb-2)*32, lane);
#pragma unroll
    for (int cb = 0; cb < 4; ++cb) acc[cb] = MFMA(a, wf[kb][cb], acc[cb]);
  }
#pragma unroll
  for (int cb = 0; cb < 4; ++cb)
#pragma unroll
    for (int j = 0; j < 4; ++j) acc[cb][j] += bv[cb];
  const int rbase = R + ((lane >> 4) << 2), cl = lane & 15;
#pragma unroll
  for (int cb = 0; cb < 4; ++cb)
#pragma unroll
    for (int j = 0; j < 4; ++j){
      int r = rbase + j;
      if (r < N) out[(size_t)r*64 + cb*16 + cl] = f2bf(acc[cb][j]);
    }
  // fused x_nl for next layer
  xpose_store(sT[w], lane, acc);
  f4v ac2[4] = {f4v{0,0,0,0}, f4v{0,0,0,0}, f4v{0,0,0,0}, f4v{0,0,0,0}};
#pragma unroll
  for (int kb = 0; kb < 2; ++kb){
    bfrag a = xpose_load(sT[w], lane, kb);
#pragma unroll
    for (int cb = 0; cb < 4; ++cb) ac2[cb] = MFMA(a, wn[kb][cb], ac2[cb]);
  }
#pragma unroll
  for (int cb = 0; cb < 4; ++cb)
#pragma unroll
    for (int j = 0; j < 4; ++j){
      int r = rbase + j;
      if (r < N) xnl[(size_t)r*64 + cb*16 + cl] = f2bf(ac2[cb][j] + bnv[cb]);
    }
}

// ---------------- GEMM layer-agg: K=256 over 4 embs + zg1*max ----------------
__global__ __launch_bounds__(256) void gemmL_k(const u16* __restrict__ e0,
    const u16* __restrict__ e1, const u16* __restrict__ e2, const u16* __restrict__ e3,
    const u16* __restrict__ Wf, const float* __restrict__ bias,
    const u16* __restrict__ mbuf, const float* __restrict__ Z_lagg,
    u16* __restrict__ out, int N){
  const int lane = threadIdx.x & 63, w = threadIdx.x >> 6;
  const int R = blockIdx.x*64 + w*16;
  const u16* Ab[4] = {e0, e1, e2, e3};
  bfrag wf[8][4];
#pragma unroll
  for (int kb = 0; kb < 8; ++kb)
#pragma unroll
    for (int cb = 0; cb < 4; ++cb) wf[kb][cb] = ldW(Wf, kb, cb, lane);
  float bv[4];
#pragma unroll
  for (int cb = 0; cb < 4; ++cb) bv[cb] = bias[cb*16 + (lane & 15)];
  const float zg1 = Z_lagg[1];
  const long ra = (R + (lane & 15) < N) ? (R + (lane & 15)) : (N - 1);
  f4v acc[4] = {f4v{0,0,0,0}, f4v{0,0,0,0}, f4v{0,0,0,0}, f4v{0,0,0,0}};
#pragma unroll
  for (int kb = 0; kb < 8; ++kb){
    bfrag a = ldA(Ab[kb >> 1], ra, (kb & 1)*32, lane);
#pragma unroll
    for (int cb = 0; cb < 4; ++cb) acc[cb] = MFMA(a, wf[kb][cb], acc[cb]);
  }
  const int rbase = R + ((lane >> 4) << 2), cl = lane & 15;
#pragma unroll
  for (int cb = 0; cb < 4; ++cb)
#pragma unroll
    for (int j = 0; j < 4; ++j){
      int r = rbase + j;
      if (r < N){
        float v = acc[cb][j] + bv[cb] + zg1*bf2f(mbuf[(size_t)r*64 + cb*16 + cl]);
        out[(size_t)r*64 + cb*16 + cl] = f2bf(v);
      }
    }
}

// ---------------- fused feed-forward head: relu(mix@W1+b1)@W2 + b2 -> fp32 out ----------------
__global__ __launch_bounds__(256) void ff12_k(const u16* __restrict__ A,
    const u16* __restrict__ Wf1, const float* __restrict__ b1,
    const u16* __restrict__ Wf2, const float* __restrict__ b2,
    float* __restrict__ out, int N){
  __shared__ u16 sT[4][1024];
  const int lane = threadIdx.x & 63, w = threadIdx.x >> 6;
  const int R = blockIdx.x*64 + w*16;
  bfrag wf1[2][4], wf2[2][4];
#pragma unroll
  for (int kb = 0; kb < 2; ++kb)
#pragma unroll
    for (int cb = 0; cb < 4; ++cb){ wf1[kb][cb] = ldW(Wf1, kb, cb, lane); wf2[kb][cb] = ldW(Wf2, kb, cb, lane); }
  float bv1[4], bv2[4];
#pragma unroll
  for (int cb = 0; cb < 4; ++cb){ bv1[cb] = b1[cb*16 + (lane & 15)]; bv2[cb] = b2[cb*16 + (lane & 15)]; }
  const long ra = (R + (lane & 15) < N) ? (R + (lane & 15)) : (N - 1);
  f4v acc[4] = {f4v{0,0,0,0}, f4v{0,0,0,0}, f4v{0,0,0,0}, f4v{0,0,0,0}};
#pragma unroll
  for (int kb = 0; kb < 2; ++kb){
    bfrag a = ldA(A, ra, kb*32, lane);
#pragma unroll
    for (int cb = 0; cb < 4; ++cb) acc[cb] = MFMA(a, wf1[kb][cb], acc[cb]);
  }
#pragma unroll
  for (int cb = 0; cb < 4; ++cb)
#pragma unroll
    for (int j = 0; j < 4; ++j) acc[cb][j] = fmaxf(acc[cb][j] + bv1[cb], 0.f);
  xpose_store(sT[w], lane, acc);
  f4v ac2[4] = {f4v{0,0,0,0}, f4v{0,0,0,0}, f4v{0,0,0,0}, f4v{0,0,0,0}};
#pragma unroll
  for (int kb = 0; kb < 2; ++kb){
    bfrag a = xpose_load(sT[w], lane, kb);
#pragma unroll
    for (int cb = 0; cb < 4; ++cb) ac2[cb] = MFMA(a, wf2[kb][cb], ac2[cb]);
  }
  const int rbase = R + ((lane >> 4) << 2), cl = lane & 15;
#pragma unroll
  for (int cb = 0; cb < 4; ++cb)
#pragma unroll
    for (int j = 0; j < 4; ++j){
      int r = rbase + j;
      if (r < N) out[(size_t)r*64 + cb*16 + cl] = ac2[cb][j] + bv2[cb];
    }
}

// ---------------- neighbor aggregate: 4 neighbors in flight, 8B loads ----------------
__global__ __launch_bounds__(256) void gather_k(const u16* __restrict__ xnl,
    const int* __restrict__ off, const int* __restrict__ cnt, const int* __restrict__ perm,
    const float* __restrict__ Z_agg, int layer, u16* __restrict__ xn, int N){
  const int lane = threadIdx.x & 63, w = threadIdx.x >> 6;
  const int r = blockIdx.x*4 + w;
  if (r >= N) return;
  const float za0 = Z_agg[layer*3+0], za1 = Z_agg[layer*3+1], za2 = Z_agg[layer*3+2];
  const int e0 = off[r], deg = cnt[r];
  const int q = lane & 15, g = lane >> 4;   // g = neighbor slot, q = channel quarter
  const float NI = -3.402823466e38f;
  float s0 = 0.f, s1 = 0.f, s2 = 0.f, s3 = 0.f;
  float m0 = NI, m1 = NI, m2 = NI, m3 = NI;
  for (int base = 0; base < deg; base += 64){
    int nrem = deg - base; if (nrem > 64) nrem = 64;
    int pe = (lane < nrem) ? perm[e0 + base + lane] : 0;
    for (int j = 0; j < nrem; j += 4){
      int idx = j + g;
      int s = __shfl(pe, idx, 64);
      if (idx < nrem){
        ushort4 u = *reinterpret_cast<const ushort4*>(xnl + (size_t)s*64 + q*4);
        float a = bf2f(u.x), b = bf2f(u.y), c = bf2f(u.z), d = bf2f(u.w);
        s0 += a; s1 += b; s2 += c; s3 += d;
        m0 = fmaxf(m0, a); m1 = fmaxf(m1, b); m2 = fmaxf(m2, c); m3 = fmaxf(m3, d);
      }
    }
  }
  s0 += __shfl_xor(s0, 16, 64); s1 += __shfl_xor(s1, 16, 64);
  s2 += __shfl_xor(s2, 16, 64); s3 += __shfl_xor(s3, 16, 64);
  s0 += __shfl_xor(s0, 32, 64); s1 += __shfl_xor(s1, 32, 64);
  s2 += __shfl_xor(s2, 32, 64); s3 += __shfl_xor(s3, 32, 64);
  m0 = fmaxf(m0, __shfl_xor(m0, 16, 64)); m1 = fmaxf(m1, __shfl_xor(m1, 16, 64));
  m2 = fmaxf(m2, __shfl_xor(m2, 16, 64)); m3 = fmaxf(m3, __shfl_xor(m3, 16, 64));
  m0 = fmaxf(m0, __shfl_xor(m0, 32, 64)); m1 = fmaxf(m1, __shfl_xor(m1, 32, 64));
  m2 = fmaxf(m2, __shfl_xor(m2, 32, 64)); m3 = fmaxf(m3, __shfl_xor(m3, 32, 64));
  if (g == 0){
    float inv = 1.f / fmaxf((float)deg, 1.f);
    float gz = (deg > 0) ? 1.f : 0.f;
    ushort4 o;
    o.x = f2bf(za0*s0 + za1*s0*inv + za2*gz*m0);
    o.y = f2bf(za0*s1 + za1*s1*inv + za2*gz*m1);
    o.z = f2bf(za0*s2 + za1*s2*inv + za2*gz*m2);
    o.w = f2bf(za0*s3 + za1*s3*inv + za2*gz*m3);
    *reinterpret_cast<ushort4*>(xn + (size_t)r*64 + q*4) = o;
  }
}

// ---------------- elementwise max of 4 embs ----------------
__global__ void maxe_k(const u16* __restrict__ e0, const u16* __restrict__ e1,
                       const u16* __restrict__ e2, const u16* __restrict__ e3,
                       u16* __restrict__ m, long total8){
  long i = (long)blockIdx.x*blockDim.x + threadIdx.x;
  if (i >= total8) return;
  const uint4 a = reinterpret_cast<const uint4*>(e0)[i];
  const uint4 b = reinterpret_cast<const uint4*>(e1)[i];
  const uint4 c = reinterpret_cast<const uint4*>(e2)[i];
  const uint4 d = reinterpret_cast<const uint4*>(e3)[i];
  const u32 av[4] = {a.x, a.y, a.z, a.w}, bv[4] = {b.x, b.y, b.z, b.w};
  const u32 cv[4] = {c.x, c.y, c.z, c.w}, dv[4] = {d.x, d.y, d.z, d.w};
  u32 ov[4];
#pragma unroll
  for (int t = 0; t < 4; ++t){
    float lo = fmaxf(fmaxf(bf2f((u16)(av[t] & 0xffffu)), bf2f((u16)(bv[t] & 0xffffu))),
                     fmaxf(bf2f((u16)(cv[t] & 0xffffu)), bf2f((u16)(dv[t] & 0xffffu))));
    float hi = fmaxf(fmaxf(bf2f((u16)(av[t] >> 16)), bf2f((u16)(bv[t] >> 16))),
                     fmaxf(bf2f((u16)(cv[t] >> 16)), bf2f((u16)(dv[t] >> 16))));
    ov[t] = (u32)f2bf(lo) | (((u32)f2bf(hi)) << 16);
  }
  uint4 o; o.x = ov[0]; o.y = ov[1]; o.z = ov[2]; o.w = ov[3];
  reinterpret_cast<uint4*>(m)[i] = o;
}

extern "C" void kernel_launch(void* const* d_in, const int* in_sizes, int n_in,
                              void* d_out, int out_size, void* d_ws, size_t ws_size,
                              hipStream_t stream){
  const float* x      = (const float*)d_in[0];
  const int*   ei     = (const int*)  d_in[1];
  const float* W_pre  = (const float*)d_in[2];
  const float* b_pre  = (const float*)d_in[3];
  const float* W_self = (const float*)d_in[4];
  const float* b_self = (const float*)d_in[5];
  const float* W_nbr  = (const float*)d_in[6];
  const float* b_nbr  = (const float*)d_in[7];
  const float* W_comb = (const float*)d_in[8];
  const float* b_comb = (const float*)d_in[9];
  const float* W_lc   = (const float*)d_in[10];
  const float* b_lc   = (const float*)d_in[11];
  const float* ln_g   = (const float*)d_in[12];
  const float* ln_b   = (const float*)d_in[13];
  const float* prelu  = (const float*)d_in[14];
  const float* W_lagg = (const float*)d_in[15];
  const float* b_lagg = (const float*)d_in[16];
  const float* W_ff1  = (const float*)d_in[17];
  const float* b_ff1  = (const float*)d_in[18];
  const float* W_ff2  = (const float*)d_in[19];
  const float* b_ff2  = (const float*)d_in[20];
  const float* Z_agg  = (const float*)d_in[21];
  const float* Z_comb = (const float*)d_in[22];
  const float* Z_act  = (const float*)d_in[23];
  const float* Z_lc   = (const float*)d_in[24];
  const float* Z_lagg = (const float*)d_in[25];

  const int N = in_sizes[0] / 128;
  const int E = in_sizes[1] / 2;
  const int* src = ei;
  const int* tgt = ei + E;

  char* p = (char*)d_ws;
  auto carve = [&](size_t bytes)->void*{
    void* q = (void*)p;
    p += (bytes + 255) & ~(size_t)255;
    return q;
  };
  int* cnt_i = (int*)carve((size_t)N*4);
  int* off   = (int*)carve((size_t)N*4);
  int* cur   = (int*)carve((size_t)N*4);
  int* bsum  = (int*)carve(4096*4);
  int* perm  = (int*)carve((size_t)E*4);
  float* WsWct = (float*)carve(3*4096*4);
  float* bsWct = (float*)carve(3*64*4);
  float* W1eff = (float*)carve(3*4096*4);
  float* W2eff = (float*)carve(3*4096*4);
  float* beff  = (float*)carve(3*64*4);
  float* Wlceff= (float*)carve(2*8192*4);
  float* blceff= (float*)carve(2*64*4);
  float* Wle   = (float*)carve(16384*4);
  float* ble   = (float*)carve(64*4);
  u16* pWpre = (u16*)carve(8192*2);
  u16* pWnbr = (u16*)carve(3*4096*2);
  u16* pW1   = (u16*)carve(3*4096*2);
  u16* pW2   = (u16*)carve(3*4096*2);
  u16* pWlc  = (u16*)carve(2*8192*2);
  u16* pWlagg= (u16*)carve(16384*2);
  u16* pWff1 = (u16*)carve(4096*2);
  u16* pWff2 = (u16*)carve(4096*2);
  const size_t AB = (size_t)N*64*2;
  u16* emb0 = (u16*)carve(AB);
  u16* emb1 = (u16*)carve(AB);
  u16* emb2 = (u16*)carve(AB);
  u16* emb3 = (u16*)carve(AB);
  u16* xbuf = (u16*)carve(AB);
  u16* xnl  = (u16*)carve(AB);
  u16* xn   = (u16*)carve(AB);
  u16* mixb = (u16*)carve(AB);
  u16* mbuf = (u16*)carve(AB);

  const int chunkN = DIV_UP(N, NCH);

  // ---- CSR build (XCD-owned chunks) ----
  hipMemsetAsync(cnt_i, 0, (size_t)N*4, stream);
  count_x_k<<<1024,256,0,stream>>>(tgt, cnt_i, E, chunkN, N);
  const int nb = DIV_UP(N, SCAN_B);
  blockscan_k<<<nb,SCAN_B,0,stream>>>(cnt_i, off, bsum, N);
  scan2_k<<<1,SCAN_B,0,stream>>>(bsum, nb);
  addback_k<<<DIV_UP(N,256),256,0,stream>>>(off, bsum, cur, N);
  scatter_x_k<<<1024,256,0,stream>>>(src, tgt, cur, perm, E, chunkN, N);

  // ---- weight prep ----
  matW_k<<<3*65,64,0,stream>>>(W_self, W_comb, b_self, WsWct, bsWct);
  buildAll_k<<<DIV_UP(45440,256),256,0,stream>>>(W_self, W_comb, b_self, b_comb, Z_comb,
                                                 WsWct, bsWct, W_lc, b_lc, Z_lc,
                                                 W_lagg, b_lagg, Z_lagg,
                                                 W1eff, W2eff, beff, Wlceff, blceff, Wle, ble);

  PackJobs pj;
  pj.src[0] = W_pre;  pj.dst[0] = pWpre;  pj.nkb[0] = 4;
  for (int i = 0; i < 3; ++i){
    pj.src[1+i] = W_nbr + i*4096; pj.dst[1+i] = pWnbr + i*4096; pj.nkb[1+i] = 2;
    pj.src[4+i] = W1eff + i*4096; pj.dst[4+i] = pW1   + i*4096; pj.nkb[4+i] = 2;
    pj.src[7+i] = W2eff + i*4096; pj.dst[7+i] = pW2   + i*4096; pj.nkb[7+i] = 2;
  }
  pj.src[10] = Wlceff;        pj.dst[10] = pWlc;        pj.nkb[10] = 4;
  pj.src[11] = Wlceff + 8192; pj.dst[11] = pWlc + 8192; pj.nkb[11] = 4;
  pj.src[12] = Wle;   pj.dst[12] = pWlagg; pj.nkb[12] = 8;
  pj.src[13] = W_ff1; pj.dst[13] = pWff1;  pj.nkb[13] = 2;
  pj.src[14] = W_ff2; pj.dst[14] = pWff2;  pj.nkb[14] = 2;
  pack_all_k<<<15*8,256,0,stream>>>(pj);

  const int G64 = DIV_UP(N, 64);

  // ---- preprocess (+ fused x_nl layer 0) ----
  gemmP_k<<<G64,256,0,stream>>>(x, pWpre, b_pre, pWnbr, b_nbr, emb0, xnl, N);

  // ---- layers ----
  u16* embs[4] = {emb0, emb1, emb2, emb3};
  const u16* xin = emb0;
  for (int i = 0; i < 3; ++i){
    gather_k<<<DIV_UP(N,4),256,0,stream>>>(xnl, off, cnt_i, perm, Z_agg, i, xn, N);
    gemmC_k<<<G64,256,0,stream>>>(xin, xn, pW1 + i*4096, pW2 + i*4096,
                                  beff + i*64, ln_g + i*64, ln_b + i*64,
                                  Z_act + i*2, prelu + i, embs[i+1], N);
    if (i < 2){
      lc_k<<<G64,256,0,stream>>>(embs[i], embs[i+1], pWlc + i*8192, blceff + i*64,
                                 pWnbr + (i+1)*4096, b_nbr + (i+1)*64, xbuf, xnl, N);
      xin = xbuf;
    }
  }

  // ---- layer agg + head ----
  maxe_k<<<DIV_UP(N*64/8,256),256,0,stream>>>(emb0, emb1, emb2, emb3, mbuf, (long)N*64/8);
  gemmL_k<<<G64,256,0,stream>>>(emb0, emb1, emb2, emb3, pWlagg, ble, mbuf, Z_lagg, mixb, N);
  ff12_k<<<G64,256,0,stream>>>(mixb, pWff1, b_ff1, pWff2, b_ff2, (float*)d_out, N);
}